// Round 1
// baseline (728.386 us; speedup 1.0000x reference)
//
#include <hip/hip_runtime.h>
#include <math.h>

typedef __attribute__((ext_vector_type(8))) short short8;
typedef __attribute__((ext_vector_type(4))) float f32x4;
typedef unsigned short ushort_t;

__device__ __forceinline__ float bf2f(ushort_t u) {
    return __uint_as_float(((unsigned int)u) << 16);
}
__device__ __forceinline__ ushort_t f2bf(float f) {
    unsigned int u = __float_as_uint(f);
    unsigned int r = u + 0x7fffu + ((u >> 16) & 1u);   // RTN-even
    return (ushort_t)(r >> 16);
}

__device__ __forceinline__ void async_cp16(const void* g, void* l) {
    __builtin_amdgcn_global_load_lds((const __attribute__((address_space(1))) void*)g,
                                     (__attribute__((address_space(3))) void*)l, 16, 0, 0);
}

// ---------------------------------------------------------------------------
// f32 -> bf16 weight conversion
// ---------------------------------------------------------------------------
__global__ __launch_bounds__(256) void conv_bf16(const float* __restrict__ in,
                                                 ushort_t* __restrict__ out, int n) {
    int i = blockIdx.x * 256 + threadIdx.x;
    if (i < n) out[i] = f2bf(in[i]);
}

// ---------------------------------------------------------------------------
// style modulation: s = style @ (w/sqrt(512)).T + b  for ada1 and ada2
// ---------------------------------------------------------------------------
__global__ __launch_bounds__(256) void style_kernel(const float* __restrict__ style,
        const float* __restrict__ w1, const float* __restrict__ b1,
        const float* __restrict__ w2, const float* __restrict__ b2,
        float* __restrict__ s1, float* __restrict__ s2) {
    int t = blockIdx.x * 256 + threadIdx.x;      // [0, 16384)
    int which = t >> 13;
    int idx = t & 8191;
    int b = idx >> 10, j = idx & 1023;
    const float* w = which ? w2 : w1;
    const float* bb = which ? b2 : b1;
    const float* st = style + b * 512;
    const float* wr = w + (size_t)j * 512;
    float acc = 0.f;
    for (int k = 0; k < 512; ++k) acc += st[k] * wr[k];
    float v = acc * 0.04419417382415922f + bb[j];   // 1/sqrt(512)
    (which ? s2 : s1)[idx] = v;
}

// ---------------------------------------------------------------------------
// instance-norm stats over tokens (axis=1): partial + finalize
// x layout (8, 4096, 512)
// ---------------------------------------------------------------------------
__global__ __launch_bounds__(512) void stats_part(const float* __restrict__ x,
        float* __restrict__ psum, float* __restrict__ psq) {
    int b = blockIdx.x >> 5;          // 8
    int ch = blockIdx.x & 31;         // 32 chunks of 128 tokens
    int c = threadIdx.x;              // 512
    const float* p = x + ((size_t)b * 4096 + (size_t)ch * 128) * 512 + c;
    float s = 0.f, q = 0.f;
    for (int t = 0; t < 128; ++t) {
        float v = p[(size_t)t * 512];
        s += v; q += v * v;
    }
    psum[(size_t)blockIdx.x * 512 + c] = s;
    psq [(size_t)blockIdx.x * 512 + c] = q;
}

__global__ __launch_bounds__(256) void stats_fin(const float* __restrict__ psum,
        const float* __restrict__ psq, float* __restrict__ mean, float* __restrict__ rstd) {
    int i = blockIdx.x * 256 + threadIdx.x;   // 4096 = b*512 + c
    int b = i >> 9, c = i & 511;
    float s = 0.f, q = 0.f;
    for (int ch = 0; ch < 32; ++ch) {
        s += psum[(size_t)(b * 32 + ch) * 512 + c];
        q += psq [(size_t)(b * 32 + ch) * 512 + c];
    }
    float m = s * (1.f / 4096.f);
    float v = q * (1.f / 4096.f) - m * m;
    mean[i] = m;
    rstd[i] = rsqrtf(v + 1e-5f);
}

// ---------------------------------------------------------------------------
// adain apply: xn = gamma*(x-mean)*rstd + beta  -> bf16
// ---------------------------------------------------------------------------
__global__ __launch_bounds__(256) void adain_kernel(const float* __restrict__ x,
        const float* __restrict__ s, const float* __restrict__ mean,
        const float* __restrict__ rstd, ushort_t* __restrict__ xn) {
    size_t i4 = (size_t)blockIdx.x * 256 + threadIdx.x;   // 4,194,304 threads
    size_t e = i4 * 4;
    int b = (int)(e >> 21);
    int c = (int)(e & 511);
    float4 xv = *(const float4*)(x + e);
    float vals[4] = {xv.x, xv.y, xv.z, xv.w};
    ushort_t o[4];
#pragma unroll
    for (int j = 0; j < 4; ++j) {
        int cc = c + j;
        float g  = s[b * 1024 + cc];
        float be = s[b * 1024 + 512 + cc];
        float mn = mean[b * 512 + cc];
        float rs = rstd[b * 512 + cc];
        o[j] = f2bf(g * (vals[j] - mn) * rs + be);
    }
    unsigned long long packed = (unsigned long long)o[0] |
        ((unsigned long long)o[1] << 16) | ((unsigned long long)o[2] << 32) |
        ((unsigned long long)o[3] << 48);
    *(unsigned long long*)(xn + e) = packed;
}

// ---------------------------------------------------------------------------
// GEMM: C[m][n] = sum_k A[m][k] * W[n][k] (+bias, epilogue variants)
// A: bf16 (M,K) row-major; W: bf16 (N,K) row-major. 128x128 tile, BK=64,
// 4 waves (2x2), each wave 64x64 via 16x16x32 bf16 MFMA.
// EPI: 0 = bf16 store, 1 = +resid -> f32 store, 2 = gelu -> bf16, 3 = f32 +=
// ---------------------------------------------------------------------------
template<int EPI>
__global__ __launch_bounds__(256) void gemm_bt(
        const ushort_t* __restrict__ A, const ushort_t* __restrict__ Bw,
        const float* __restrict__ bias, const float* __restrict__ resid,
        float* __restrict__ outf, ushort_t* __restrict__ outh,
        int M, int N, int K) {
    __shared__ short As[128 * 64];
    __shared__ short Bs[128 * 64];
    const int tid  = threadIdx.x;
    const int lane = tid & 63;
    const int wave = tid >> 6;
    const int wr = wave >> 1, wc = wave & 1;
    const long tile_m = (long)blockIdx.x * 128;
    const long tile_n = (long)blockIdx.y * 128;

    f32x4 acc[4][4];
#pragma unroll
    for (int m = 0; m < 4; ++m)
#pragma unroll
        for (int n = 0; n < 4; ++n)
#pragma unroll
            for (int r = 0; r < 4; ++r) acc[m][n][r] = 0.f;

    const int lr = lane >> 3;        // row within 8-row chunk
    const int l8 = lane & 7;         // col group
    const int lm = lane & 15;        // fragment row
    const int lk = lane >> 4;        // fragment k-group

    for (int k0 = 0; k0 < K; k0 += 64) {
#pragma unroll
        for (int i = 0; i < 4; ++i) {
            int ch = wave * 4 + i;               // 16 chunks of 8 rows x 64 cols
            int row = ch * 8 + lr;
            int col = l8 * 8;
            const ushort_t* ga = A  + (tile_m + row) * (long)K + k0 + col;
            const ushort_t* gb = Bw + (tile_n + row) * (long)K + k0 + col;
            async_cp16(ga, As + ch * 512);
            async_cp16(gb, Bs + ch * 512);
        }
        __syncthreads();
#pragma unroll
        for (int kk = 0; kk < 2; ++kk) {
            short8 af[4], bf[4];
#pragma unroll
            for (int m = 0; m < 4; ++m)
                af[m] = *(const short8*)&As[(wr * 64 + m * 16 + lm) * 64 + kk * 32 + lk * 8];
#pragma unroll
            for (int n = 0; n < 4; ++n)
                bf[n] = *(const short8*)&Bs[(wc * 64 + n * 16 + lm) * 64 + kk * 32 + lk * 8];
#pragma unroll
            for (int m = 0; m < 4; ++m)
#pragma unroll
                for (int n = 0; n < 4; ++n)
                    acc[m][n] = __builtin_amdgcn_mfma_f32_16x16x32_bf16(af[m], bf[n], acc[m][n], 0, 0, 0);
        }
        __syncthreads();
    }

    // epilogue: D row = (lane>>4)*4 + r, col = lane&15 (verified layout)
#pragma unroll
    for (int m = 0; m < 4; ++m) {
        long row0 = tile_m + wr * 64 + m * 16 + lk * 4;
#pragma unroll
        for (int n = 0; n < 4; ++n) {
            long col = tile_n + wc * 64 + n * 16 + lm;
            float bb = bias[col];
#pragma unroll
            for (int r = 0; r < 4; ++r) {
                long o = (row0 + r) * (long)N + col;
                float v = acc[m][n][r] + bb;
                if (EPI == 0) {
                    outh[o] = f2bf(v);
                } else if (EPI == 1) {
                    outf[o] = v + resid[o];
                } else if (EPI == 2) {
                    float g = 0.5f * v * (1.0f + erff(v * 0.70710678118654752f));
                    outh[o] = f2bf(g);
                } else {
                    outf[o] += v;
                }
            }
        }
    }
}

// ---------------------------------------------------------------------------
// window attention: one wave per (branch, window, head).
// qkv: (32768, 1536) bf16 token-major; q/k/v at col 0/512/1024 + branch*256 + head*32
// ---------------------------------------------------------------------------
__global__ __launch_bounds__(64) void attn_kernel(const ushort_t* __restrict__ qkv,
        const float* __restrict__ rpb1, const float* __restrict__ rpb2,
        ushort_t* __restrict__ attno) {
    __shared__ float klds[64][36];
    __shared__ float vlds[64][36];
    int bid = blockIdx.x;
    int branch = bid >> 12;               // 4096 blocks per branch
    int w_idx  = (bid >> 3) & 511;        // 512 windows (b-major)
    int head   = bid & 7;
    int b = w_idx >> 6, win = w_idx & 63;
    int wh = win >> 3, ww = win & 7;
    int lane = threadIdx.x;
    int ti = lane >> 3, tj = lane & 7;
    int hh = wh * 8 + ti;                 // window-frame (rolled-frame) coords
    int wp = ww * 8 + tj;
    int hs = branch ? ((hh + 4) & 63) : hh;   // source/dest token (roll cancels)
    int wsp = branch ? ((wp + 4) & 63) : wp;
    int n = hs * 64 + wsp;
    int c0 = branch * 256 + head * 32;
    const ushort_t* rowp = qkv + (size_t)(b * 4096 + n) * 1536;

    float q[32];
#pragma unroll
    for (int v8 = 0; v8 < 4; ++v8) {
        short8 t = *(const short8*)(rowp + c0 + v8 * 8);
#pragma unroll
        for (int i = 0; i < 8; ++i) q[v8 * 8 + i] = bf2f((ushort_t)t[i]);
    }
#pragma unroll
    for (int v8 = 0; v8 < 4; ++v8) {
        short8 tk = *(const short8*)(rowp + 512  + c0 + v8 * 8);
        short8 tv = *(const short8*)(rowp + 1024 + c0 + v8 * 8);
#pragma unroll
        for (int i = 0; i < 8; ++i) {
            klds[lane][v8 * 8 + i] = bf2f((ushort_t)tk[i]);
            vlds[lane][v8 * 8 + i] = bf2f((ushort_t)tv[i]);
        }
    }
    __syncthreads();

    const float* rpb = branch ? rpb2 : rpb1;
    int code_i = 0;
    if (branch) {
        int gh = (hh < 56) ? 0 : (hh < 60 ? 1 : 2);
        int gw = (wp < 56) ? 0 : (wp < 60 ? 1 : 2);
        code_i = gh * 3 + gw;
    }

    float s[64];
    float mx = -1e30f;
#pragma unroll
    for (int j = 0; j < 64; ++j) {
        int rj = j >> 3, cj = j & 7;
        float acc = 0.f;
        const float* kr = &klds[j][0];
#pragma unroll
        for (int d = 0; d < 32; ++d) acc += q[d] * kr[d];
        // qk_scale = 1/sqrt(32); rpi idx = (ri-rj)+(ci-cj)+29 (reference's += quirk)
        float sc = acc * 0.17677669529663687f + rpb[((ti - rj) + (tj - cj) + 29) * 8 + head];
        if (branch) {
            int hj = wh * 8 + rj, wj = ww * 8 + cj;
            int gh = (hj < 56) ? 0 : (hj < 60 ? 1 : 2);
            int gw = (wj < 56) ? 0 : (wj < 60 ? 1 : 2);
            if (gh * 3 + gw != code_i) sc -= 100.f;
        }
        s[j] = sc;
        mx = fmaxf(mx, sc);
    }
    float sum = 0.f;
#pragma unroll
    for (int j = 0; j < 64; ++j) { float e = __expf(s[j] - mx); s[j] = e; sum += e; }
    float inv = 1.f / sum;
    float o[32];
#pragma unroll
    for (int d = 0; d < 32; ++d) o[d] = 0.f;
#pragma unroll
    for (int j = 0; j < 64; ++j) {
        float p = s[j] * inv;
        const float* vr = &vlds[j][0];
#pragma unroll
        for (int d = 0; d < 32; ++d) o[d] += p * vr[d];
    }
    ushort_t* op = attno + (size_t)(b * 4096 + n) * 512 + c0;
#pragma unroll
    for (int v8 = 0; v8 < 4; ++v8) {
        short8 t;
#pragma unroll
        for (int i = 0; i < 8; ++i) t[i] = (short)f2bf(o[v8 * 8 + i]);
        *(short8*)(op + v8 * 8) = t;
    }
}

// ---------------------------------------------------------------------------
extern "C" void kernel_launch(void* const* d_in, const int* in_sizes, int n_in,
                              void* d_out, int out_size, void* d_ws, size_t ws_size,
                              hipStream_t stream) {
    const float* x      = (const float*)d_in[0];
    const float* style  = (const float*)d_in[1];
    const float* ada1_w = (const float*)d_in[2];
    const float* ada1_b = (const float*)d_in[3];
    const float* qkv_w  = (const float*)d_in[4];
    const float* qkv_b  = (const float*)d_in[5];
    const float* rpb1   = (const float*)d_in[6];
    const float* rpb2   = (const float*)d_in[7];
    const float* proj_w = (const float*)d_in[8];
    const float* proj_b = (const float*)d_in[9];
    const float* ada2_w = (const float*)d_in[10];
    const float* ada2_b = (const float*)d_in[11];
    const float* mlp_w1 = (const float*)d_in[12];
    const float* mlp_b1 = (const float*)d_in[13];
    const float* mlp_w2 = (const float*)d_in[14];
    const float* mlp_b2 = (const float*)d_in[15];
    float* outf = (float*)d_out;

    char* W = (char*)d_ws;
    ushort_t* qkvb    = (ushort_t*)(W);                      // 96 MB (32768 x 1536)
    ushort_t* attno   = (ushort_t*)(W + 100663296);          // 32 MB (32768 x 512)
    ushort_t* hbuf    = (ushort_t*)(W);                      // 128 MB overlay (32768 x 2048)
    ushort_t* xn      = (ushort_t*)(W + 134217728);          // 32 MB (32768 x 512)
    ushort_t* qkv_wb  = (ushort_t*)(W + 167772160);          // 1536x512
    ushort_t* proj_wb = (ushort_t*)(W + 167772160 + 1572864);
    ushort_t* w1b     = (ushort_t*)(W + 167772160 + 2097152);
    ushort_t* w2b     = (ushort_t*)(W + 167772160 + 4194304);
    float* freg  = (float*)(W + 167772160 + 6291456);
    float* s1    = freg;
    float* s2    = freg + 8192;
    float* mean1 = freg + 16384;
    float* rstd1 = freg + 20480;
    float* mean2 = freg + 24576;
    float* rstd2 = freg + 28672;
    float* psum  = freg + 32768;    // 8*32*512
    float* psq   = freg + 163840;   // 8*32*512

    // weights -> bf16
    conv_bf16<<<(786432 + 255) / 256, 256, 0, stream>>>(qkv_w, qkv_wb, 786432);
    conv_bf16<<<(262144 + 255) / 256, 256, 0, stream>>>(proj_w, proj_wb, 262144);
    conv_bf16<<<(1048576 + 255) / 256, 256, 0, stream>>>(mlp_w1, w1b, 1048576);
    conv_bf16<<<(1048576 + 255) / 256, 256, 0, stream>>>(mlp_w2, w2b, 1048576);

    // style modulation (both adains)
    style_kernel<<<64, 256, 0, stream>>>(style, ada1_w, ada1_b, ada2_w, ada2_b, s1, s2);

    // adain1
    stats_part<<<256, 512, 0, stream>>>(x, psum, psq);
    stats_fin<<<16, 256, 0, stream>>>(psum, psq, mean1, rstd1);
    adain_kernel<<<16384, 256, 0, stream>>>(x, s1, mean1, rstd1, xn);

    // qkv
    gemm_bt<0><<<dim3(256, 12), 256, 0, stream>>>(xn, qkv_wb, qkv_b, nullptr, nullptr, qkvb, 32768, 1536, 512);

    // window attention (both branches)
    attn_kernel<<<8192, 64, 0, stream>>>(qkvb, rpb1, rpb2, attno);

    // proj + residual -> d_out (f32)
    gemm_bt<1><<<dim3(256, 4), 256, 0, stream>>>(attno, proj_wb, proj_b, x, outf, nullptr, 32768, 512, 512);

    // adain2 on d_out
    stats_part<<<256, 512, 0, stream>>>(outf, psum, psq);
    stats_fin<<<16, 256, 0, stream>>>(psum, psq, mean2, rstd2);
    adain_kernel<<<16384, 256, 0, stream>>>(outf, s2, mean2, rstd2, xn);

    // mlp
    gemm_bt<2><<<dim3(256, 16), 256, 0, stream>>>(xn, w1b, mlp_b1, nullptr, nullptr, hbuf, 32768, 2048, 512);
    gemm_bt<3><<<dim3(256, 4), 256, 0, stream>>>(hbuf, w2b, mlp_b2, nullptr, outf, nullptr, 32768, 512, 2048);
}

// Round 2
// 553.522 us; speedup vs baseline: 1.3159x; 1.3159x over previous
//
#include <hip/hip_runtime.h>
#include <math.h>

typedef __attribute__((ext_vector_type(8))) short short8;
typedef __attribute__((ext_vector_type(4))) float f32x4;
typedef unsigned short ushort_t;

__device__ __forceinline__ float bf2f(ushort_t u) {
    return __uint_as_float(((unsigned int)u) << 16);
}
__device__ __forceinline__ ushort_t f2bf(float f) {
    unsigned int u = __float_as_uint(f);
    unsigned int r = u + 0x7fffu + ((u >> 16) & 1u);   // RTN-even
    return (ushort_t)(r >> 16);
}

__device__ __forceinline__ void async_cp16(const void* g, void* l) {
    __builtin_amdgcn_global_load_lds((const __attribute__((address_space(1))) void*)g,
                                     (__attribute__((address_space(3))) void*)l, 16, 0, 0);
}

// ---------------------------------------------------------------------------
// f32 -> bf16 weight conversion
// ---------------------------------------------------------------------------
__global__ __launch_bounds__(256) void conv_bf16(const float* __restrict__ in,
                                                 ushort_t* __restrict__ out, int n) {
    int i = blockIdx.x * 256 + threadIdx.x;
    if (i < n) out[i] = f2bf(in[i]);
}

// ---------------------------------------------------------------------------
// style modulation: s = style @ (w/sqrt(512)).T + b  for ada1 and ada2
// ---------------------------------------------------------------------------
__global__ __launch_bounds__(256) void style_kernel(const float* __restrict__ style,
        const float* __restrict__ w1, const float* __restrict__ b1,
        const float* __restrict__ w2, const float* __restrict__ b2,
        float* __restrict__ s1, float* __restrict__ s2) {
    int t = blockIdx.x * 256 + threadIdx.x;      // [0, 16384)
    int which = t >> 13;
    int idx = t & 8191;
    int b = idx >> 10, j = idx & 1023;
    const float* w = which ? w2 : w1;
    const float* bb = which ? b2 : b1;
    const float* st = style + b * 512;
    const float* wr = w + (size_t)j * 512;
    float acc = 0.f;
    for (int k = 0; k < 512; ++k) acc += st[k] * wr[k];
    float v = acc * 0.04419417382415922f + bb[j];   // 1/sqrt(512)
    (which ? s2 : s1)[idx] = v;
}

// ---------------------------------------------------------------------------
// instance-norm stats over tokens (axis=1): partial + finalize
// ---------------------------------------------------------------------------
__global__ __launch_bounds__(512) void stats_part(const float* __restrict__ x,
        float* __restrict__ psum, float* __restrict__ psq) {
    int b = blockIdx.x >> 5;
    int ch = blockIdx.x & 31;
    int c = threadIdx.x;
    const float* p = x + ((size_t)b * 4096 + (size_t)ch * 128) * 512 + c;
    float s = 0.f, q = 0.f;
    for (int t = 0; t < 128; ++t) {
        float v = p[(size_t)t * 512];
        s += v; q += v * v;
    }
    psum[(size_t)blockIdx.x * 512 + c] = s;
    psq [(size_t)blockIdx.x * 512 + c] = q;
}

__global__ __launch_bounds__(256) void stats_fin(const float* __restrict__ psum,
        const float* __restrict__ psq, float* __restrict__ mean, float* __restrict__ rstd) {
    int i = blockIdx.x * 256 + threadIdx.x;   // 4096 = b*512 + c
    int b = i >> 9, c = i & 511;
    float s = 0.f, q = 0.f;
    for (int ch = 0; ch < 32; ++ch) {
        s += psum[(size_t)(b * 32 + ch) * 512 + c];
        q += psq [(size_t)(b * 32 + ch) * 512 + c];
    }
    float m = s * (1.f / 4096.f);
    float v = q * (1.f / 4096.f) - m * m;
    mean[i] = m;
    rstd[i] = rsqrtf(v + 1e-5f);
}

// ---------------------------------------------------------------------------
// adain apply: xn = gamma*(x-mean)*rstd + beta  -> bf16
// ---------------------------------------------------------------------------
__global__ __launch_bounds__(256) void adain_kernel(const float* __restrict__ x,
        const float* __restrict__ s, const float* __restrict__ mean,
        const float* __restrict__ rstd, ushort_t* __restrict__ xn) {
    size_t i4 = (size_t)blockIdx.x * 256 + threadIdx.x;
    size_t e = i4 * 4;
    int b = (int)(e >> 21);
    int c = (int)(e & 511);
    float4 xv = *(const float4*)(x + e);
    float vals[4] = {xv.x, xv.y, xv.z, xv.w};
    ushort_t o[4];
#pragma unroll
    for (int j = 0; j < 4; ++j) {
        int cc = c + j;
        float g  = s[b * 1024 + cc];
        float be = s[b * 1024 + 512 + cc];
        float mn = mean[b * 512 + cc];
        float rs = rstd[b * 512 + cc];
        o[j] = f2bf(g * (vals[j] - mn) * rs + be);
    }
    unsigned long long packed = (unsigned long long)o[0] |
        ((unsigned long long)o[1] << 16) | ((unsigned long long)o[2] << 32) |
        ((unsigned long long)o[3] << 48);
    *(unsigned long long*)(xn + e) = packed;
}

// ---------------------------------------------------------------------------
// GEMM 256x256 tile, BK=64, 8 waves (2Mx4N), 8-phase pipelined schedule.
// C[m][n] = sum_k A[m][k] * W[n][k] (+bias, epilogue variants)
// A: bf16 (M,K) row-major; W: bf16 (N,K) row-major. M%256==0, N%256==0, K%64==0.
// LDS: A [2 dbuf][2 half][128][64] bf16 at 0; B same at ushort 32768. 128 KiB.
// XOR swizzle: ushort col ^= (row&7)<<3 on ds_read; inverse-swizzled global
// source with linear global_load_lds dest (both-sides rule).
// Prefetch map at tile t (c=t&1): ph1->(t+1).A0, ph2->(t+1).A1,
// ph3->(t+2).B0, ph4->(t+2).B1; vmcnt(4) only at ph4.
// EPI: 0 = bf16 store, 1 = +resid -> f32 store, 2 = gelu -> bf16, 3 = f32 +=
// ---------------------------------------------------------------------------
template<int EPI>
__global__ __launch_bounds__(512, 2) void gemm256(
        const ushort_t* __restrict__ A, const ushort_t* __restrict__ Bw,
        const float* __restrict__ bias, const float* __restrict__ resid,
        float* __restrict__ outf, ushort_t* __restrict__ outh,
        int M, int N, int K, int gridN) {
    __shared__ ushort_t lds[65536];   // 128 KiB
    const int tid  = threadIdx.x;
    const int lane = tid & 63;
    const int wave = tid >> 6;
    const int wm = wave >> 2, wn = wave & 3;

    // XCD-aware block swizzle (grid is a multiple of 8 for all our shapes)
    const int nwg = gridDim.x;
    const int cpx = nwg >> 3;
    const int orig = blockIdx.x;
    const int wgid = (orig & 7) * cpx + (orig >> 3);
    const int bm = wgid / gridN, bn = wgid % gridN;
    const long tile_m = (long)bm * 256;
    const long tile_n = (long)bn * 256;
    const int nt = K >> 6;

    f32x4 acc[8][4];
#pragma unroll
    for (int m = 0; m < 8; ++m)
#pragma unroll
        for (int n = 0; n < 4; ++n)
#pragma unroll
            for (int r = 0; r < 4; ++r) acc[m][n][r] = 0.f;

    // staging: half-tile = 128 rows x 64 cols bf16 = 16 KB; 2 x 16B per thread.
    // chunk = tid + rnd*512 -> (row=chunk>>3, granule g=chunk&7); LDS dest is
    // linear (wave-uniform base + lane*16); global source granule = g^(row&7).
    auto stageA = [&](int d, int h, int kt) {
#pragma unroll
        for (int rnd = 0; rnd < 2; ++rnd) {
            int chunk = tid + rnd * 512;
            int row = chunk >> 3;
            int g = chunk & 7;
            int gsw = g ^ (row & 7);
            const ushort_t* src = A + (tile_m + h * 128 + row) * (long)K + kt * 64 + gsw * 8;
            async_cp16(src, lds + d * 16384 + h * 8192 + chunk * 8);
        }
    };
    auto stageB = [&](int d, int h, int kt) {
#pragma unroll
        for (int rnd = 0; rnd < 2; ++rnd) {
            int chunk = tid + rnd * 512;
            int row = chunk >> 3;
            int g = chunk & 7;
            int gsw = g ^ (row & 7);
            const ushort_t* src = Bw + (tile_n + h * 128 + row) * (long)K + kt * 64 + gsw * 8;
            async_cp16(src, lds + 32768 + d * 16384 + h * 8192 + chunk * 8);
        }
    };

    // prologue: tile0 all 4 half-tiles + tile1 B-halves; drain to 4 in flight
    stageA(0, 0, 0); stageA(0, 1, 0);
    stageB(0, 0, 0); stageB(0, 1, 0);
    {
        int t1 = (nt > 1) ? 1 : 0;
        stageB(1, 0, t1); stageB(1, 1, t1);
    }
    asm volatile("s_waitcnt vmcnt(4)" ::: "memory");
    __builtin_amdgcn_sched_barrier(0);
    __builtin_amdgcn_s_barrier();

    const int lm = lane & 15;
    const int kg = lane >> 4;

    for (int t = 0; t < nt; ++t) {
        const int c = t & 1;
        const int abase = c * 16384 + wm * 8192;
        const int bbase = 32768 + c * 16384 + (wn >> 1) * 8192;
        const int tn  = (t + 1 < nt) ? t + 1 : 0;
        const int tn2 = (t + 2 < nt) ? t + 2 : 0;
        short8 bfr[4][2];

#pragma unroll
        for (int q = 0; q < 4; ++q) {
            // ds-read this phase's A quadrant (rows q*32..q*32+31 of wave half)
            short8 af[2][2];
#pragma unroll
            for (int mq = 0; mq < 2; ++mq) {
                int ra = q * 32 + mq * 16 + lm;
#pragma unroll
                for (int ks = 0; ks < 2; ++ks) {
                    int colu = (ks * 32 + kg * 8) ^ ((ra & 7) << 3);
                    af[mq][ks] = *(const short8*)&lds[abase + ra * 64 + colu];
                }
            }
            if (q == 0) {
                // B frags for the whole K-tile (held in regs)
#pragma unroll
                for (int n = 0; n < 4; ++n) {
                    int rb = (wn & 1) * 64 + n * 16 + lm;
#pragma unroll
                    for (int ks = 0; ks < 2; ++ks) {
                        int colu = (ks * 32 + kg * 8) ^ ((rb & 7) << 3);
                        bfr[n][ks] = *(const short8*)&lds[bbase + rb * 64 + colu];
                    }
                }
            }
            // prefetch issue (1 half-tile per phase)
            if      (q == 0) stageA(c ^ 1, 0, tn);
            else if (q == 1) stageA(c ^ 1, 1, tn);
            else if (q == 2) stageB(c, 0, tn2);
            else             stageB(c, 1, tn2);

            __builtin_amdgcn_s_barrier();
            asm volatile("s_waitcnt lgkmcnt(0)" ::: "memory");
            __builtin_amdgcn_sched_barrier(0);
            __builtin_amdgcn_s_setprio(1);
#pragma unroll
            for (int mq = 0; mq < 2; ++mq)
#pragma unroll
                for (int n = 0; n < 4; ++n)
#pragma unroll
                    for (int ks = 0; ks < 2; ++ks)
                        acc[q * 2 + mq][n] = __builtin_amdgcn_mfma_f32_16x16x32_bf16(
                            af[mq][ks], bfr[n][ks], acc[q * 2 + mq][n], 0, 0, 0);
            __builtin_amdgcn_s_setprio(0);
            if (q == 3) {
                asm volatile("s_waitcnt vmcnt(4)" ::: "memory");
                __builtin_amdgcn_sched_barrier(0);
            }
            __builtin_amdgcn_s_barrier();
        }
    }

    // epilogue: D row = (lane>>4)*4 + r, col = lane&15
#pragma unroll
    for (int m = 0; m < 8; ++m) {
        long row0 = tile_m + wm * 128 + m * 16 + kg * 4;
#pragma unroll
        for (int n = 0; n < 4; ++n) {
            long col = tile_n + wn * 64 + n * 16 + lm;
            float bb = bias[col];
#pragma unroll
            for (int r = 0; r < 4; ++r) {
                long o = (row0 + r) * (long)N + col;
                float v = acc[m][n][r] + bb;
                if (EPI == 0) {
                    outh[o] = f2bf(v);
                } else if (EPI == 1) {
                    outf[o] = v + resid[o];
                } else if (EPI == 2) {
                    float g = 0.5f * v * (1.0f + erff(v * 0.70710678118654752f));
                    outh[o] = f2bf(g);
                } else {
                    outf[o] += v;
                }
            }
        }
    }
}

// ---------------------------------------------------------------------------
// window attention: one wave per (branch, window, head).
// ---------------------------------------------------------------------------
__global__ __launch_bounds__(64) void attn_kernel(const ushort_t* __restrict__ qkv,
        const float* __restrict__ rpb1, const float* __restrict__ rpb2,
        ushort_t* __restrict__ attno) {
    __shared__ float klds[64][36];
    __shared__ float vlds[64][36];
    int bid = blockIdx.x;
    int branch = bid >> 12;
    int w_idx  = (bid >> 3) & 511;
    int head   = bid & 7;
    int b = w_idx >> 6, win = w_idx & 63;
    int wh = win >> 3, ww = win & 7;
    int lane = threadIdx.x;
    int ti = lane >> 3, tj = lane & 7;
    int hh = wh * 8 + ti;
    int wp = ww * 8 + tj;
    int hs = branch ? ((hh + 4) & 63) : hh;
    int wsp = branch ? ((wp + 4) & 63) : wp;
    int n = hs * 64 + wsp;
    int c0 = branch * 256 + head * 32;
    const ushort_t* rowp = qkv + (size_t)(b * 4096 + n) * 1536;

    float q[32];
#pragma unroll
    for (int v8 = 0; v8 < 4; ++v8) {
        short8 t = *(const short8*)(rowp + c0 + v8 * 8);
#pragma unroll
        for (int i = 0; i < 8; ++i) q[v8 * 8 + i] = bf2f((ushort_t)t[i]);
    }
#pragma unroll
    for (int v8 = 0; v8 < 4; ++v8) {
        short8 tk = *(const short8*)(rowp + 512  + c0 + v8 * 8);
        short8 tv = *(const short8*)(rowp + 1024 + c0 + v8 * 8);
#pragma unroll
        for (int i = 0; i < 8; ++i) {
            klds[lane][v8 * 8 + i] = bf2f((ushort_t)tk[i]);
            vlds[lane][v8 * 8 + i] = bf2f((ushort_t)tv[i]);
        }
    }
    __syncthreads();

    const float* rpb = branch ? rpb2 : rpb1;
    int code_i = 0;
    if (branch) {
        int gh = (hh < 56) ? 0 : (hh < 60 ? 1 : 2);
        int gw = (wp < 56) ? 0 : (wp < 60 ? 1 : 2);
        code_i = gh * 3 + gw;
    }

    float s[64];
    float mx = -1e30f;
#pragma unroll
    for (int j = 0; j < 64; ++j) {
        int rj = j >> 3, cj = j & 7;
        float acc = 0.f;
        const float* kr = &klds[j][0];
#pragma unroll
        for (int d = 0; d < 32; ++d) acc += q[d] * kr[d];
        float sc = acc * 0.17677669529663687f + rpb[((ti - rj) + (tj - cj) + 29) * 8 + head];
        if (branch) {
            int hj = wh * 8 + rj, wj = ww * 8 + cj;
            int gh = (hj < 56) ? 0 : (hj < 60 ? 1 : 2);
            int gw = (wj < 56) ? 0 : (wj < 60 ? 1 : 2);
            if (gh * 3 + gw != code_i) sc -= 100.f;
        }
        s[j] = sc;
        mx = fmaxf(mx, sc);
    }
    float sum = 0.f;
#pragma unroll
    for (int j = 0; j < 64; ++j) { float e = __expf(s[j] - mx); s[j] = e; sum += e; }
    float inv = 1.f / sum;
    float o[32];
#pragma unroll
    for (int d = 0; d < 32; ++d) o[d] = 0.f;
#pragma unroll
    for (int j = 0; j < 64; ++j) {
        float p = s[j] * inv;
        const float* vr = &vlds[j][0];
#pragma unroll
        for (int d = 0; d < 32; ++d) o[d] += p * vr[d];
    }
    ushort_t* op = attno + (size_t)(b * 4096 + n) * 512 + c0;
#pragma unroll
    for (int v8 = 0; v8 < 4; ++v8) {
        short8 t;
#pragma unroll
        for (int i = 0; i < 8; ++i) t[i] = (short)f2bf(o[v8 * 8 + i]);
        *(short8*)(op + v8 * 8) = t;
    }
}

// ---------------------------------------------------------------------------
extern "C" void kernel_launch(void* const* d_in, const int* in_sizes, int n_in,
                              void* d_out, int out_size, void* d_ws, size_t ws_size,
                              hipStream_t stream) {
    const float* x      = (const float*)d_in[0];
    const float* style  = (const float*)d_in[1];
    const float* ada1_w = (const float*)d_in[2];
    const float* ada1_b = (const float*)d_in[3];
    const float* qkv_w  = (const float*)d_in[4];
    const float* qkv_b  = (const float*)d_in[5];
    const float* rpb1   = (const float*)d_in[6];
    const float* rpb2   = (const float*)d_in[7];
    const float* proj_w = (const float*)d_in[8];
    const float* proj_b = (const float*)d_in[9];
    const float* ada2_w = (const float*)d_in[10];
    const float* ada2_b = (const float*)d_in[11];
    const float* mlp_w1 = (const float*)d_in[12];
    const float* mlp_b1 = (const float*)d_in[13];
    const float* mlp_w2 = (const float*)d_in[14];
    const float* mlp_b2 = (const float*)d_in[15];
    float* outf = (float*)d_out;

    char* W = (char*)d_ws;
    ushort_t* qkvb    = (ushort_t*)(W);                      // 96 MB (32768 x 1536)
    ushort_t* attno   = (ushort_t*)(W + 100663296);          // 32 MB (32768 x 512)
    ushort_t* hbuf    = (ushort_t*)(W);                      // 128 MB overlay (32768 x 2048)
    ushort_t* xn      = (ushort_t*)(W + 134217728);          // 32 MB (32768 x 512)
    ushort_t* qkv_wb  = (ushort_t*)(W + 167772160);          // 1536x512
    ushort_t* proj_wb = (ushort_t*)(W + 167772160 + 1572864);
    ushort_t* w1b     = (ushort_t*)(W + 167772160 + 2097152);
    ushort_t* w2b     = (ushort_t*)(W + 167772160 + 4194304);
    float* freg  = (float*)(W + 167772160 + 6291456);
    float* s1    = freg;
    float* s2    = freg + 8192;
    float* mean1 = freg + 16384;
    float* rstd1 = freg + 20480;
    float* mean2 = freg + 24576;
    float* rstd2 = freg + 28672;
    float* psum  = freg + 32768;
    float* psq   = freg + 163840;

    // weights -> bf16
    conv_bf16<<<(786432 + 255) / 256, 256, 0, stream>>>(qkv_w, qkv_wb, 786432);
    conv_bf16<<<(262144 + 255) / 256, 256, 0, stream>>>(proj_w, proj_wb, 262144);
    conv_bf16<<<(1048576 + 255) / 256, 256, 0, stream>>>(mlp_w1, w1b, 1048576);
    conv_bf16<<<(1048576 + 255) / 256, 256, 0, stream>>>(mlp_w2, w2b, 1048576);

    // style modulation (both adains)
    style_kernel<<<64, 256, 0, stream>>>(style, ada1_w, ada1_b, ada2_w, ada2_b, s1, s2);

    // adain1
    stats_part<<<256, 512, 0, stream>>>(x, psum, psq);
    stats_fin<<<16, 256, 0, stream>>>(psum, psq, mean1, rstd1);
    adain_kernel<<<16384, 256, 0, stream>>>(x, s1, mean1, rstd1, xn);

    // qkv: (32768,1536,512) -> grid 128*6 = 768
    gemm256<0><<<dim3(768), 512, 0, stream>>>(xn, qkv_wb, qkv_b, nullptr, nullptr, qkvb, 32768, 1536, 512, 6);

    // window attention (both branches)
    attn_kernel<<<8192, 64, 0, stream>>>(qkvb, rpb1, rpb2, attno);

    // proj + residual -> d_out (f32): (32768,512,512) -> grid 256
    gemm256<1><<<dim3(256), 512, 0, stream>>>(attno, proj_wb, proj_b, x, outf, nullptr, 32768, 512, 512, 2);

    // adain2 on d_out
    stats_part<<<256, 512, 0, stream>>>(outf, psum, psq);
    stats_fin<<<16, 256, 0, stream>>>(psum, psq, mean2, rstd2);
    adain_kernel<<<16384, 256, 0, stream>>>(outf, s2, mean2, rstd2, xn);

    // mlp1: (32768,2048,512) -> grid 128*8 = 1024
    gemm256<2><<<dim3(1024), 512, 0, stream>>>(xn, w1b, mlp_b1, nullptr, nullptr, hbuf, 32768, 2048, 512, 8);
    // mlp2: (32768,512,2048) -> grid 256
    gemm256<3><<<dim3(256), 512, 0, stream>>>(hbuf, w2b, mlp_b2, nullptr, outf, nullptr, 32768, 512, 2048, 2);
}

// Round 3
// 532.500 us; speedup vs baseline: 1.3679x; 1.0395x over previous
//
#include <hip/hip_runtime.h>
#include <math.h>

typedef __attribute__((ext_vector_type(8))) short short8;
typedef __attribute__((ext_vector_type(4))) float f32x4;
typedef unsigned short ushort_t;

__device__ __forceinline__ float bf2f(ushort_t u) {
    return __uint_as_float(((unsigned int)u) << 16);
}
__device__ __forceinline__ ushort_t f2bf(float f) {
    unsigned int u = __float_as_uint(f);
    unsigned int r = u + 0x7fffu + ((u >> 16) & 1u);   // RTN-even
    return (ushort_t)(r >> 16);
}

__device__ __forceinline__ void async_cp16(const void* g, void* l) {
    __builtin_amdgcn_global_load_lds((const __attribute__((address_space(1))) void*)g,
                                     (__attribute__((address_space(3))) void*)l, 16, 0, 0);
}

// tanh-form gelu via hardware exp: max abs err ~3e-4*|x| (well under tolerance)
__device__ __forceinline__ float fast_gelu(float v) {
    float u2 = 2.0f * v * (0.7978845608028654f + 0.0356774081f * v * v);
    float e = __expf(u2);
    float r = 1.0f / (e + 1.0f);
    return v - v * r;            // v * (1+tanh(u))/2
}

// ---------------------------------------------------------------------------
// f32 -> bf16 weight conversion
// ---------------------------------------------------------------------------
__global__ __launch_bounds__(256) void conv_bf16(const float* __restrict__ in,
                                                 ushort_t* __restrict__ out, int n) {
    int i = blockIdx.x * 256 + threadIdx.x;
    if (i < n) out[i] = f2bf(in[i]);
}

// ---------------------------------------------------------------------------
// style modulation: s = style @ (w/sqrt(512)).T + b  for ada1 and ada2
// ---------------------------------------------------------------------------
__global__ __launch_bounds__(256) void style_kernel(const float* __restrict__ style,
        const float* __restrict__ w1, const float* __restrict__ b1,
        const float* __restrict__ w2, const float* __restrict__ b2,
        float* __restrict__ s1, float* __restrict__ s2) {
    int t = blockIdx.x * 256 + threadIdx.x;      // [0, 16384)
    int which = t >> 13;
    int idx = t & 8191;
    int b = idx >> 10, j = idx & 1023;
    const float* w = which ? w2 : w1;
    const float* bb = which ? b2 : b1;
    const float* st = style + b * 512;
    const float* wr = w + (size_t)j * 512;
    float acc = 0.f;
    for (int k = 0; k < 512; ++k) acc += st[k] * wr[k];
    float v = acc * 0.04419417382415922f + bb[j];   // 1/sqrt(512)
    (which ? s2 : s1)[idx] = v;
}

// ---------------------------------------------------------------------------
// instance-norm stats over tokens (axis=1): partial + finalize
// ---------------------------------------------------------------------------
__global__ __launch_bounds__(512) void stats_part(const float* __restrict__ x,
        float* __restrict__ psum, float* __restrict__ psq) {
    int b = blockIdx.x >> 5;
    int ch = blockIdx.x & 31;
    int c = threadIdx.x;
    const float* p = x + ((size_t)b * 4096 + (size_t)ch * 128) * 512 + c;
    float s = 0.f, q = 0.f;
    for (int t = 0; t < 128; ++t) {
        float v = p[(size_t)t * 512];
        s += v; q += v * v;
    }
    psum[(size_t)blockIdx.x * 512 + c] = s;
    psq [(size_t)blockIdx.x * 512 + c] = q;
}

__global__ __launch_bounds__(256) void stats_fin(const float* __restrict__ psum,
        const float* __restrict__ psq, float* __restrict__ mean, float* __restrict__ rstd) {
    int i = blockIdx.x * 256 + threadIdx.x;   // 4096 = b*512 + c
    int b = i >> 9, c = i & 511;
    float s = 0.f, q = 0.f;
    for (int ch = 0; ch < 32; ++ch) {
        s += psum[(size_t)(b * 32 + ch) * 512 + c];
        q += psq [(size_t)(b * 32 + ch) * 512 + c];
    }
    float m = s * (1.f / 4096.f);
    float v = q * (1.f / 4096.f) - m * m;
    mean[i] = m;
    rstd[i] = rsqrtf(v + 1e-5f);
}

// ---------------------------------------------------------------------------
// adain apply: xn = gamma*(x-mean)*rstd + beta  -> bf16
// ---------------------------------------------------------------------------
__global__ __launch_bounds__(256) void adain_kernel(const float* __restrict__ x,
        const float* __restrict__ s, const float* __restrict__ mean,
        const float* __restrict__ rstd, ushort_t* __restrict__ xn) {
    size_t i4 = (size_t)blockIdx.x * 256 + threadIdx.x;
    size_t e = i4 * 4;
    int b = (int)(e >> 21);
    int c = (int)(e & 511);
    float4 xv = *(const float4*)(x + e);
    float vals[4] = {xv.x, xv.y, xv.z, xv.w};
    ushort_t o[4];
#pragma unroll
    for (int j = 0; j < 4; ++j) {
        int cc = c + j;
        float g  = s[b * 1024 + cc];
        float be = s[b * 1024 + 512 + cc];
        float mn = mean[b * 512 + cc];
        float rs = rstd[b * 512 + cc];
        o[j] = f2bf(g * (vals[j] - mn) * rs + be);
    }
    unsigned long long packed = (unsigned long long)o[0] |
        ((unsigned long long)o[1] << 16) | ((unsigned long long)o[2] << 32) |
        ((unsigned long long)o[3] << 48);
    *(unsigned long long*)(xn + e) = packed;
}

// ---------------------------------------------------------------------------
// GEMM 256x256 tile, BK=64, 8 waves (2Mx4N), 8-phase pipelined schedule.
// EPI: 0 = bf16 store, 1 = +resid -> f32 store, 2 = gelu -> bf16, 3 = f32 +=
// ---------------------------------------------------------------------------
template<int EPI>
__global__ __launch_bounds__(512, 2) void gemm256(
        const ushort_t* __restrict__ A, const ushort_t* __restrict__ Bw,
        const float* __restrict__ bias, const float* __restrict__ resid,
        float* __restrict__ outf, ushort_t* __restrict__ outh,
        int M, int N, int K, int gridN) {
    __shared__ ushort_t lds[65536];   // 128 KiB
    const int tid  = threadIdx.x;
    const int lane = tid & 63;
    const int wave = tid >> 6;
    const int wm = wave >> 2, wn = wave & 3;

    const int nwg = gridDim.x;
    const int cpx = nwg >> 3;
    const int orig = blockIdx.x;
    const int wgid = (orig & 7) * cpx + (orig >> 3);
    const int bm = wgid / gridN, bn = wgid % gridN;
    const long tile_m = (long)bm * 256;
    const long tile_n = (long)bn * 256;
    const int nt = K >> 6;

    f32x4 acc[8][4];
#pragma unroll
    for (int m = 0; m < 8; ++m)
#pragma unroll
        for (int n = 0; n < 4; ++n)
#pragma unroll
            for (int r = 0; r < 4; ++r) acc[m][n][r] = 0.f;

    auto stageA = [&](int d, int h, int kt) {
#pragma unroll
        for (int rnd = 0; rnd < 2; ++rnd) {
            int chunk = tid + rnd * 512;
            int row = chunk >> 3;
            int g = chunk & 7;
            int gsw = g ^ (row & 7);
            const ushort_t* src = A + (tile_m + h * 128 + row) * (long)K + kt * 64 + gsw * 8;
            async_cp16(src, lds + d * 16384 + h * 8192 + chunk * 8);
        }
    };
    auto stageB = [&](int d, int h, int kt) {
#pragma unroll
        for (int rnd = 0; rnd < 2; ++rnd) {
            int chunk = tid + rnd * 512;
            int row = chunk >> 3;
            int g = chunk & 7;
            int gsw = g ^ (row & 7);
            const ushort_t* src = Bw + (tile_n + h * 128 + row) * (long)K + kt * 64 + gsw * 8;
            async_cp16(src, lds + 32768 + d * 16384 + h * 8192 + chunk * 8);
        }
    };

    stageA(0, 0, 0); stageA(0, 1, 0);
    stageB(0, 0, 0); stageB(0, 1, 0);
    {
        int t1 = (nt > 1) ? 1 : 0;
        stageB(1, 0, t1); stageB(1, 1, t1);
    }
    asm volatile("s_waitcnt vmcnt(4)" ::: "memory");
    __builtin_amdgcn_sched_barrier(0);
    __builtin_amdgcn_s_barrier();

    const int lm = lane & 15;
    const int kg = lane >> 4;

    for (int t = 0; t < nt; ++t) {
        const int c = t & 1;
        const int abase = c * 16384 + wm * 8192;
        const int bbase = 32768 + c * 16384 + (wn >> 1) * 8192;
        const int tn  = (t + 1 < nt) ? t + 1 : 0;
        const int tn2 = (t + 2 < nt) ? t + 2 : 0;
        short8 bfr[4][2];

#pragma unroll
        for (int q = 0; q < 4; ++q) {
            short8 af[2][2];
#pragma unroll
            for (int mq = 0; mq < 2; ++mq) {
                int ra = q * 32 + mq * 16 + lm;
#pragma unroll
                for (int ks = 0; ks < 2; ++ks) {
                    int colu = (ks * 32 + kg * 8) ^ ((ra & 7) << 3);
                    af[mq][ks] = *(const short8*)&lds[abase + ra * 64 + colu];
                }
            }
            if (q == 0) {
#pragma unroll
                for (int n = 0; n < 4; ++n) {
                    int rb = (wn & 1) * 64 + n * 16 + lm;
#pragma unroll
                    for (int ks = 0; ks < 2; ++ks) {
                        int colu = (ks * 32 + kg * 8) ^ ((rb & 7) << 3);
                        bfr[n][ks] = *(const short8*)&lds[bbase + rb * 64 + colu];
                    }
                }
            }
            if      (q == 0) stageA(c ^ 1, 0, tn);
            else if (q == 1) stageA(c ^ 1, 1, tn);
            else if (q == 2) stageB(c, 0, tn2);
            else             stageB(c, 1, tn2);

            __builtin_amdgcn_s_barrier();
            asm volatile("s_waitcnt lgkmcnt(0)" ::: "memory");
            __builtin_amdgcn_sched_barrier(0);
            __builtin_amdgcn_s_setprio(1);
#pragma unroll
            for (int mq = 0; mq < 2; ++mq)
#pragma unroll
                for (int n = 0; n < 4; ++n)
#pragma unroll
                    for (int ks = 0; ks < 2; ++ks)
                        acc[q * 2 + mq][n] = __builtin_amdgcn_mfma_f32_16x16x32_bf16(
                            af[mq][ks], bfr[n][ks], acc[q * 2 + mq][n], 0, 0, 0);
            __builtin_amdgcn_s_setprio(0);
            if (q == 3) {
                asm volatile("s_waitcnt vmcnt(4)" ::: "memory");
                __builtin_amdgcn_sched_barrier(0);
            }
            __builtin_amdgcn_s_barrier();
        }
    }

    // epilogue: D row = (lane>>4)*4 + r, col = lane&15
#pragma unroll
    for (int m = 0; m < 8; ++m) {
        long row0 = tile_m + wm * 128 + m * 16 + kg * 4;
#pragma unroll
        for (int n = 0; n < 4; ++n) {
            long col = tile_n + wn * 64 + n * 16 + lm;
            float bb = bias[col];
#pragma unroll
            for (int r = 0; r < 4; ++r) {
                long o = (row0 + r) * (long)N + col;
                float v = acc[m][n][r] + bb;
                if (EPI == 0) {
                    outh[o] = f2bf(v);
                } else if (EPI == 1) {
                    outf[o] = v + resid[o];
                } else if (EPI == 2) {
                    outh[o] = f2bf(fast_gelu(v));
                } else {
                    outf[o] += v;
                }
            }
        }
    }
}

// ---------------------------------------------------------------------------
// window attention: one wave per (branch, window, head).
// ---------------------------------------------------------------------------
__global__ __launch_bounds__(64) void attn_kernel(const ushort_t* __restrict__ qkv,
        const float* __restrict__ rpb1, const float* __restrict__ rpb2,
        ushort_t* __restrict__ attno) {
    __shared__ float klds[64][36];
    __shared__ float vlds[64][36];
    int bid = blockIdx.x;
    int branch = bid >> 12;
    int w_idx  = (bid >> 3) & 511;
    int head   = bid & 7;
    int b = w_idx >> 6, win = w_idx & 63;
    int wh = win >> 3, ww = win & 7;
    int lane = threadIdx.x;
    int ti = lane >> 3, tj = lane & 7;
    int hh = wh * 8 + ti;
    int wp = ww * 8 + tj;
    int hs = branch ? ((hh + 4) & 63) : hh;
    int wsp = branch ? ((wp + 4) & 63) : wp;
    int n = hs * 64 + wsp;
    int c0 = branch * 256 + head * 32;
    const ushort_t* rowp = qkv + (size_t)(b * 4096 + n) * 1536;

    float q[32];
#pragma unroll
    for (int v8 = 0; v8 < 4; ++v8) {
        short8 t = *(const short8*)(rowp + c0 + v8 * 8);
#pragma unroll
        for (int i = 0; i < 8; ++i) q[v8 * 8 + i] = bf2f((ushort_t)t[i]);
    }
#pragma unroll
    for (int v8 = 0; v8 < 4; ++v8) {
        short8 tk = *(const short8*)(rowp + 512  + c0 + v8 * 8);
        short8 tv = *(const short8*)(rowp + 1024 + c0 + v8 * 8);
#pragma unroll
        for (int i = 0; i < 8; ++i) {
            klds[lane][v8 * 8 + i] = bf2f((ushort_t)tk[i]);
            vlds[lane][v8 * 8 + i] = bf2f((ushort_t)tv[i]);
        }
    }
    __syncthreads();

    const float* rpb = branch ? rpb2 : rpb1;
    int code_i = 0;
    if (branch) {
        int gh = (hh < 56) ? 0 : (hh < 60 ? 1 : 2);
        int gw = (wp < 56) ? 0 : (wp < 60 ? 1 : 2);
        code_i = gh * 3 + gw;
    }

    float s[64];
    float mx = -1e30f;
#pragma unroll
    for (int j = 0; j < 64; ++j) {
        int rj = j >> 3, cj = j & 7;
        const float4* kr4 = (const float4*)&klds[j][0];
        float4 k0 = kr4[0], k1 = kr4[1], k2 = kr4[2], k3 = kr4[3];
        float4 k4 = kr4[4], k5 = kr4[5], k6 = kr4[6], k7 = kr4[7];
        float acc =
            q[0]*k0.x + q[1]*k0.y + q[2]*k0.z + q[3]*k0.w +
            q[4]*k1.x + q[5]*k1.y + q[6]*k1.z + q[7]*k1.w +
            q[8]*k2.x + q[9]*k2.y + q[10]*k2.z + q[11]*k2.w +
            q[12]*k3.x + q[13]*k3.y + q[14]*k3.z + q[15]*k3.w +
            q[16]*k4.x + q[17]*k4.y + q[18]*k4.z + q[19]*k4.w +
            q[20]*k5.x + q[21]*k5.y + q[22]*k5.z + q[23]*k5.w +
            q[24]*k6.x + q[25]*k6.y + q[26]*k6.z + q[27]*k6.w +
            q[28]*k7.x + q[29]*k7.y + q[30]*k7.z + q[31]*k7.w;
        float sc = acc * 0.17677669529663687f + rpb[((ti - rj) + (tj - cj) + 29) * 8 + head];
        if (branch) {
            int hj = wh * 8 + rj, wj = ww * 8 + cj;
            int gh = (hj < 56) ? 0 : (hj < 60 ? 1 : 2);
            int gw = (wj < 56) ? 0 : (wj < 60 ? 1 : 2);
            if (gh * 3 + gw != code_i) sc -= 100.f;
        }
        s[j] = sc;
        mx = fmaxf(mx, sc);
    }
    float sum = 0.f;
#pragma unroll
    for (int j = 0; j < 64; ++j) { float e = __expf(s[j] - mx); s[j] = e; sum += e; }
    float inv = 1.f / sum;
    float o[32];
#pragma unroll
    for (int d = 0; d < 32; ++d) o[d] = 0.f;
#pragma unroll
    for (int j = 0; j < 64; ++j) {
        float p = s[j] * inv;
        const float4* vr4 = (const float4*)&vlds[j][0];
#pragma unroll
        for (int d4 = 0; d4 < 8; ++d4) {
            float4 vv = vr4[d4];
            o[d4 * 4 + 0] += p * vv.x;
            o[d4 * 4 + 1] += p * vv.y;
            o[d4 * 4 + 2] += p * vv.z;
            o[d4 * 4 + 3] += p * vv.w;
        }
    }
    ushort_t* op = attno + (size_t)(b * 4096 + n) * 512 + c0;
#pragma unroll
    for (int v8 = 0; v8 < 4; ++v8) {
        short8 t;
#pragma unroll
        for (int i = 0; i < 8; ++i) t[i] = (short)f2bf(o[v8 * 8 + i]);
        *(short8*)(op + v8 * 8) = t;
    }
}

// ---------------------------------------------------------------------------
extern "C" void kernel_launch(void* const* d_in, const int* in_sizes, int n_in,
                              void* d_out, int out_size, void* d_ws, size_t ws_size,
                              hipStream_t stream) {
    const float* x      = (const float*)d_in[0];
    const float* style  = (const float*)d_in[1];
    const float* ada1_w = (const float*)d_in[2];
    const float* ada1_b = (const float*)d_in[3];
    const float* qkv_w  = (const float*)d_in[4];
    const float* qkv_b  = (const float*)d_in[5];
    const float* rpb1   = (const float*)d_in[6];
    const float* rpb2   = (const float*)d_in[7];
    const float* proj_w = (const float*)d_in[8];
    const float* proj_b = (const float*)d_in[9];
    const float* ada2_w = (const float*)d_in[10];
    const float* ada2_b = (const float*)d_in[11];
    const float* mlp_w1 = (const float*)d_in[12];
    const float* mlp_b1 = (const float*)d_in[13];
    const float* mlp_w2 = (const float*)d_in[14];
    const float* mlp_b2 = (const float*)d_in[15];
    float* outf = (float*)d_out;

    char* W = (char*)d_ws;
    ushort_t* qkvb    = (ushort_t*)(W);                      // 96 MB (32768 x 1536)
    ushort_t* attno   = (ushort_t*)(W + 100663296);          // 32 MB (32768 x 512)
    ushort_t* hbuf    = (ushort_t*)(W);                      // 128 MB overlay (32768 x 2048)
    ushort_t* xn      = (ushort_t*)(W + 134217728);          // 32 MB (32768 x 512)
    ushort_t* qkv_wb  = (ushort_t*)(W + 167772160);          // 1536x512
    ushort_t* proj_wb = (ushort_t*)(W + 167772160 + 1572864);
    ushort_t* w1b     = (ushort_t*)(W + 167772160 + 2097152);
    ushort_t* w2b     = (ushort_t*)(W + 167772160 + 4194304);
    float* freg  = (float*)(W + 167772160 + 6291456);
    float* s1    = freg;
    float* s2    = freg + 8192;
    float* mean1 = freg + 16384;
    float* rstd1 = freg + 20480;
    float* mean2 = freg + 24576;
    float* rstd2 = freg + 28672;
    float* psum  = freg + 32768;
    float* psq   = freg + 163840;

    conv_bf16<<<(786432 + 255) / 256, 256, 0, stream>>>(qkv_w, qkv_wb, 786432);
    conv_bf16<<<(262144 + 255) / 256, 256, 0, stream>>>(proj_w, proj_wb, 262144);
    conv_bf16<<<(1048576 + 255) / 256, 256, 0, stream>>>(mlp_w1, w1b, 1048576);
    conv_bf16<<<(1048576 + 255) / 256, 256, 0, stream>>>(mlp_w2, w2b, 1048576);

    style_kernel<<<64, 256, 0, stream>>>(style, ada1_w, ada1_b, ada2_w, ada2_b, s1, s2);

    stats_part<<<256, 512, 0, stream>>>(x, psum, psq);
    stats_fin<<<16, 256, 0, stream>>>(psum, psq, mean1, rstd1);
    adain_kernel<<<16384, 256, 0, stream>>>(x, s1, mean1, rstd1, xn);

    gemm256<0><<<dim3(768), 512, 0, stream>>>(xn, qkv_wb, qkv_b, nullptr, nullptr, qkvb, 32768, 1536, 512, 6);

    attn_kernel<<<8192, 64, 0, stream>>>(qkvb, rpb1, rpb2, attno);

    gemm256<1><<<dim3(256), 512, 0, stream>>>(attno, proj_wb, proj_b, x, outf, nullptr, 32768, 512, 512, 2);

    stats_part<<<256, 512, 0, stream>>>(outf, psum, psq);
    stats_fin<<<16, 256, 0, stream>>>(psum, psq, mean2, rstd2);
    adain_kernel<<<16384, 256, 0, stream>>>(outf, s2, mean2, rstd2, xn);

    gemm256<2><<<dim3(1024), 512, 0, stream>>>(xn, w1b, mlp_b1, nullptr, nullptr, hbuf, 32768, 2048, 512, 8);
    gemm256<3><<<dim3(256), 512, 0, stream>>>(hbuf, w2b, mlp_b2, nullptr, outf, nullptr, 32768, 512, 2048, 2);
}

// Round 5
// 507.664 us; speedup vs baseline: 1.4348x; 1.0489x over previous
//
#include <hip/hip_runtime.h>
#include <math.h>

typedef __attribute__((ext_vector_type(8))) short short8;
typedef __attribute__((ext_vector_type(4))) float f32x4;
typedef unsigned short ushort_t;

__device__ __forceinline__ float bf2f(ushort_t u) {
    return __uint_as_float(((unsigned int)u) << 16);
}
__device__ __forceinline__ ushort_t f2bf(float f) {
    unsigned int u = __float_as_uint(f);
    unsigned int r = u + 0x7fffu + ((u >> 16) & 1u);   // RTN-even
    return (ushort_t)(r >> 16);
}

__device__ __forceinline__ void async_cp16(const void* g, void* l) {
    __builtin_amdgcn_global_load_lds((const __attribute__((address_space(1))) void*)g,
                                     (__attribute__((address_space(3))) void*)l, 16, 0, 0);
}

// tanh-form gelu via hardware exp: max abs err ~3e-4*|x|
__device__ __forceinline__ float fast_gelu(float v) {
    float u2 = 2.0f * v * (0.7978845608028654f + 0.0356774081f * v * v);
    float e = __expf(u2);
    float r = 1.0f / (e + 1.0f);
    return v - v * r;
}

// ---------------------------------------------------------------------------
// fused: all 4 weight conversions + zero psum2/psq2 (for proj-epilogue stats)
// ---------------------------------------------------------------------------
__global__ __launch_bounds__(256) void conv_zero(
        const float* __restrict__ qkv_w, ushort_t* __restrict__ qkv_wb,
        const float* __restrict__ proj_w, ushort_t* __restrict__ proj_wb,
        const float* __restrict__ w1, ushort_t* __restrict__ w1b,
        const float* __restrict__ w2, ushort_t* __restrict__ w2b,
        float* __restrict__ psum2, float* __restrict__ psq2) {
    int i = blockIdx.x * 256 + threadIdx.x;
    if (i < 786432) {
        qkv_wb[i] = f2bf(qkv_w[i]);
    } else if (i < 1048576) {
        int j = i - 786432; proj_wb[j] = f2bf(proj_w[j]);
    } else if (i < 2097152) {
        int j = i - 1048576; w1b[j] = f2bf(w1[j]);
    } else if (i < 3145728) {
        int j = i - 2097152; w2b[j] = f2bf(w2[j]);
    } else {
        int j = i - 3145728;       // [0, 8192)
        psum2[j] = 0.f; psq2[j] = 0.f;
    }
}

// ---------------------------------------------------------------------------
// style modulation: s = style @ (w/sqrt(512)).T + b
// ---------------------------------------------------------------------------
__global__ __launch_bounds__(256) void style_kernel(const float* __restrict__ style,
        const float* __restrict__ w1, const float* __restrict__ b1,
        const float* __restrict__ w2, const float* __restrict__ b2,
        float* __restrict__ s1, float* __restrict__ s2) {
    int t = blockIdx.x * 256 + threadIdx.x;
    int which = t >> 13;
    int idx = t & 8191;
    int b = idx >> 10, j = idx & 1023;
    const float* w = which ? w2 : w1;
    const float* bb = which ? b2 : b1;
    const float* st = style + b * 512;
    const float* wr = w + (size_t)j * 512;
    float acc = 0.f;
    for (int k = 0; k < 512; ++k) acc += st[k] * wr[k];
    float v = acc * 0.04419417382415922f + bb[j];
    (which ? s2 : s1)[idx] = v;
}

// ---------------------------------------------------------------------------
// instance-norm stats (adain1 path)
// ---------------------------------------------------------------------------
__global__ __launch_bounds__(512) void stats_part(const float* __restrict__ x,
        float* __restrict__ psum, float* __restrict__ psq) {
    int b = blockIdx.x >> 5;
    int ch = blockIdx.x & 31;
    int c = threadIdx.x;
    const float* p = x + ((size_t)b * 4096 + (size_t)ch * 128) * 512 + c;
    float s = 0.f, q = 0.f;
    for (int t = 0; t < 128; ++t) {
        float v = p[(size_t)t * 512];
        s += v; q += v * v;
    }
    psum[(size_t)blockIdx.x * 512 + c] = s;
    psq [(size_t)blockIdx.x * 512 + c] = q;
}

__global__ __launch_bounds__(256) void stats_fin(const float* __restrict__ psum,
        const float* __restrict__ psq, float* __restrict__ mean, float* __restrict__ rstd) {
    int i = blockIdx.x * 256 + threadIdx.x;
    int b = i >> 9, c = i & 511;
    float s = 0.f, q = 0.f;
    for (int ch = 0; ch < 32; ++ch) {
        s += psum[(size_t)(b * 32 + ch) * 512 + c];
        q += psq [(size_t)(b * 32 + ch) * 512 + c];
    }
    float m = s * (1.f / 4096.f);
    float v = q * (1.f / 4096.f) - m * m;
    mean[i] = m;
    rstd[i] = rsqrtf(v + 1e-5f);
}

// finalize from proj-epilogue atomics (direct [b][c] layout)
__global__ __launch_bounds__(256) void stats_fin2(const float* __restrict__ psum2,
        const float* __restrict__ psq2, float* __restrict__ mean, float* __restrict__ rstd) {
    int i = blockIdx.x * 256 + threadIdx.x;   // 4096
    float m = psum2[i] * (1.f / 4096.f);
    float v = psq2[i] * (1.f / 4096.f) - m * m;
    mean[i] = m;
    rstd[i] = rsqrtf(v + 1e-5f);
}

// ---------------------------------------------------------------------------
// adain apply
// ---------------------------------------------------------------------------
__global__ __launch_bounds__(256) void adain_kernel(const float* __restrict__ x,
        const float* __restrict__ s, const float* __restrict__ mean,
        const float* __restrict__ rstd, ushort_t* __restrict__ xn) {
    size_t i4 = (size_t)blockIdx.x * 256 + threadIdx.x;
    size_t e = i4 * 4;
    int b = (int)(e >> 21);
    int c = (int)(e & 511);
    float4 xv = *(const float4*)(x + e);
    float vals[4] = {xv.x, xv.y, xv.z, xv.w};
    ushort_t o[4];
#pragma unroll
    for (int j = 0; j < 4; ++j) {
        int cc = c + j;
        float g  = s[b * 1024 + cc];
        float be = s[b * 1024 + 512 + cc];
        float mn = mean[b * 512 + cc];
        float rs = rstd[b * 512 + cc];
        o[j] = f2bf(g * (vals[j] - mn) * rs + be);
    }
    unsigned long long packed = (unsigned long long)o[0] |
        ((unsigned long long)o[1] << 16) | ((unsigned long long)o[2] << 32) |
        ((unsigned long long)o[3] << 48);
    *(unsigned long long*)(xn + e) = packed;
}

// ---------------------------------------------------------------------------
// GEMM 256x256 tile, BK=64, 8 waves (2Mx4N), 4 phases/K-tile, persistent
// blocks (grid=256, tiles looped inside; pipeline continuous across tiles).
// RACE-FIX (round 5): vmcnt(4) must sit BEFORE the closing barrier of q3
// (each wave drains its OWN staging loads, then barrier, then anyone reads).
// vmcnt is per-wave: wait-after-barrier lets one wave read bytes another
// wave's global_load_lds hasn't landed yet (round 4's failure).
// ds_read addrs: per-thread byte-offset regs with swizzle folded in;
// double-buffer toggle = XOR bit15 (32 KiB) per K-tile; phase offsets are
// compile-time immediates.
// EPI: 0 = bf16, 1 = +resid -> f32 + column stats atomics, 2 = gelu bf16,
//      3 = f32 +=
// ---------------------------------------------------------------------------
template<int EPI>
__global__ __launch_bounds__(512, 2) void gemm256(
        const ushort_t* __restrict__ A, const ushort_t* __restrict__ Bw,
        const float* __restrict__ bias, const float* __restrict__ resid,
        float* __restrict__ outf, ushort_t* __restrict__ outh,
        float* __restrict__ psum2, float* __restrict__ psq2,
        int N, int K, int gridN, int ntiles, int lnt) {
    __shared__ ushort_t lds[65536];   // 128 KiB
    const int tid  = threadIdx.x;
    const int lane = tid & 63;
    const int wave = tid >> 6;
    const int wm = wave >> 2, wn = wave & 3;
    const int lm = lane & 15;
    const int kg = lane >> 4;
    const int nt = 1 << lnt;
    const int tpb = ntiles >> 8;

    const int orig = blockIdx.x;               // grid fixed at 256
    const int wgid = (orig & 7) * 32 + (orig >> 3);   // XCD swizzle

    // ds_read per-thread byte addresses (slot-0 state); swizzle folded in
    unsigned int lo0 = lm * 128 + ((kg * 16) ^ ((lm & 7) << 4));
    unsigned int lo1 = lo0 ^ 64;
    unsigned int vA0 = wm * 16384 + lo0;
    unsigned int vA1 = wm * 16384 + lo1;
    unsigned int vB0 = 65536 + (wn >> 1) * 16384 + (wn & 1) * 8192 + lo0;
    unsigned int vB1 = 65536 + (wn >> 1) * 16384 + (wn & 1) * 8192 + lo1;
    const char* ldsc = (const char*)lds;

    // staging per-thread element offsets (A and B identical pattern)
    int off[2][2];
#pragma unroll
    for (int rnd = 0; rnd < 2; ++rnd) {
        int chunk = tid + rnd * 512;
        int row = chunk >> 3;
        int g = chunk & 7;
        int gsw = g ^ (row & 7);
#pragma unroll
        for (int h = 0; h < 2; ++h)
            off[h][rnd] = (h * 128 + row) * K + gsw * 8;
    }

    f32x4 acc[8][4];
#pragma unroll
    for (int m = 0; m < 8; ++m)
#pragma unroll
        for (int n = 0; n < 4; ++n)
#pragma unroll
            for (int r = 0; r < 4; ++r) acc[m][n][r] = 0.f;

    // stage one half-tile (2 async 16B loads/thread)
    auto stage = [&](const ushort_t* __restrict__ mat, long bcur, long bnxt,
                     int dslot, int h, int tt, int isB) {
        long mb = (tt < nt) ? bcur : bnxt;
        int kt = tt & (nt - 1);
        const ushort_t* base = mat + mb + (kt << 6);
        ushort_t* dst = (ushort_t*)lds + isB * 32768 + dslot * 16384 + h * 8192 + tid * 8;
#pragma unroll
        for (int rnd = 0; rnd < 2; ++rnd)
            async_cp16(base + off[h][rnd], dst + rnd * 4096);
    };

    // first tile coords
    int tcur = wgid;
    int bm = tcur / gridN, bn = tcur - bm * gridN;
    long Am = (long)bm * 256 * K;
    long Bn = (long)bn * 256 * K;

    // prologue: tile0 A+B (slot0), tile0-t1 B (slot1); drain own 8, barrier
    stage(A,  Am, Am, 0, 0, 0, 0); stage(A,  Am, Am, 0, 1, 0, 0);
    stage(Bw, Bn, Bn, 0, 0, 0, 1); stage(Bw, Bn, Bn, 0, 1, 0, 1);
    stage(Bw, Bn, Bn, 1, 0, 1, 1); stage(Bw, Bn, Bn, 1, 1, 1, 1);
    asm volatile("s_waitcnt vmcnt(4)" ::: "memory");
    __builtin_amdgcn_sched_barrier(0);
    __builtin_amdgcn_s_barrier();

    for (int ti = 0; ti < tpb; ++ti) {
        // next tile coords (clamp to current at the end: dummy reloads, unread)
        int tnxt = (ti + 1 < tpb) ? tcur + 256 : tcur;
        int bm2 = tnxt / gridN, bn2 = tnxt - bm2 * gridN;
        long Am2 = (long)bm2 * 256 * K;
        long Bn2 = (long)bn2 * 256 * K;

#pragma unroll 2
        for (int t = 0; t < nt; ++t) {
            const int c = t & 1;
            short8 bfr[4][2];
#pragma unroll
            for (int q = 0; q < 4; ++q) {
                short8 af[2][2];
#pragma unroll
                for (int mq = 0; mq < 2; ++mq) {
                    af[mq][0] = *(const short8*)(ldsc + vA0 + (q * 4096 + mq * 2048));
                    af[mq][1] = *(const short8*)(ldsc + vA1 + (q * 4096 + mq * 2048));
                }
                if (q == 0) {
#pragma unroll
                    for (int n = 0; n < 4; ++n) {
                        bfr[n][0] = *(const short8*)(ldsc + vB0 + n * 2048);
                        bfr[n][1] = *(const short8*)(ldsc + vB1 + n * 2048);
                    }
                }
                if      (q == 0) stage(A,  Am, Am2, c ^ 1, 0, t + 1, 0);
                else if (q == 1) stage(A,  Am, Am2, c ^ 1, 1, t + 1, 0);
                else if (q == 2) stage(Bw, Bn, Bn2, c,     0, t + 2, 1);
                else             stage(Bw, Bn, Bn2, c,     1, t + 2, 1);

                __builtin_amdgcn_s_barrier();
                asm volatile("s_waitcnt lgkmcnt(0)" ::: "memory");
                __builtin_amdgcn_sched_barrier(0);
                __builtin_amdgcn_s_setprio(1);
#pragma unroll
                for (int mq = 0; mq < 2; ++mq)
#pragma unroll
                    for (int n = 0; n < 4; ++n)
#pragma unroll
                        for (int ks = 0; ks < 2; ++ks)
                            acc[q * 2 + mq][n] = __builtin_amdgcn_mfma_f32_16x16x32_bf16(
                                af[mq][ks], bfr[n][ks], acc[q * 2 + mq][n], 0, 0, 0);
                __builtin_amdgcn_s_setprio(0);
                if (q == 3) {
                    // drain own A(t+1),B(t+1) BEFORE the barrier (leaves B(t+2)
                    // in flight); barrier then publishes all waves' staging.
                    asm volatile("s_waitcnt vmcnt(4)" ::: "memory");
                    __builtin_amdgcn_sched_barrier(0);
                }
                __builtin_amdgcn_s_barrier();
            }
            // toggle double-buffer bit (bit 15 = 32 KiB)
            vA0 ^= 32768u; vA1 ^= 32768u; vB0 ^= 32768u; vB1 ^= 32768u;
        }

        // ---- epilogue for tile (bm,bn): D row=(lane>>4)*4+r, col=lane&15 ----
        const long tile_m = (long)bm * 256;
        const long tile_n = (long)bn * 256;
        float csum[4], csq[4];
        if (EPI == 1) {
#pragma unroll
            for (int n = 0; n < 4; ++n) { csum[n] = 0.f; csq[n] = 0.f; }
        }
#pragma unroll
        for (int m = 0; m < 8; ++m) {
            long row0 = tile_m + wm * 128 + m * 16 + kg * 4;
#pragma unroll
            for (int n = 0; n < 4; ++n) {
                long col = tile_n + wn * 64 + n * 16 + lm;
                float bb = bias[col];
#pragma unroll
                for (int r = 0; r < 4; ++r) {
                    long o = (row0 + r) * (long)N + col;
                    float v = acc[m][n][r] + bb;
                    if (EPI == 0) {
                        outh[o] = f2bf(v);
                    } else if (EPI == 1) {
                        float w = v + resid[o];
                        outf[o] = w;
                        csum[n] += w; csq[n] += w * w;
                    } else if (EPI == 2) {
                        outh[o] = f2bf(fast_gelu(v));
                    } else {
                        outf[o] += v;
                    }
                    acc[m][n][r] = 0.f;   // reset for next tile
                }
            }
        }
        if (EPI == 1) {
            int b = (int)(tile_m >> 12);
#pragma unroll
            for (int n = 0; n < 4; ++n) {
                int col = (int)(tile_n + wn * 64 + n * 16 + lm);
                atomicAdd(&psum2[b * 512 + col], csum[n]);
                atomicAdd(&psq2 [b * 512 + col], csq[n]);
            }
        }

        tcur = tnxt; bm = bm2; bn = bn2; Am = Am2; Bn = Bn2;
    }
}

// ---------------------------------------------------------------------------
// window attention: one wave per (branch, window, head).
// ---------------------------------------------------------------------------
__global__ __launch_bounds__(64) void attn_kernel(const ushort_t* __restrict__ qkv,
        const float* __restrict__ rpb1, const float* __restrict__ rpb2,
        ushort_t* __restrict__ attno) {
    __shared__ float klds[64][36];
    __shared__ float vlds[64][36];
    int bid = blockIdx.x;
    int branch = bid >> 12;
    int w_idx  = (bid >> 3) & 511;
    int head   = bid & 7;
    int b = w_idx >> 6, win = w_idx & 63;
    int wh = win >> 3, ww = win & 7;
    int lane = threadIdx.x;
    int ti = lane >> 3, tj = lane & 7;
    int hh = wh * 8 + ti;
    int wp = ww * 8 + tj;
    int hs = branch ? ((hh + 4) & 63) : hh;
    int wsp = branch ? ((wp + 4) & 63) : wp;
    int n = hs * 64 + wsp;
    int c0 = branch * 256 + head * 32;
    const ushort_t* rowp = qkv + (size_t)(b * 4096 + n) * 1536;

    float q[32];
#pragma unroll
    for (int v8 = 0; v8 < 4; ++v8) {
        short8 t = *(const short8*)(rowp + c0 + v8 * 8);
#pragma unroll
        for (int i = 0; i < 8; ++i) q[v8 * 8 + i] = bf2f((ushort_t)t[i]);
    }
#pragma unroll
    for (int v8 = 0; v8 < 4; ++v8) {
        short8 tk = *(const short8*)(rowp + 512  + c0 + v8 * 8);
        short8 tv = *(const short8*)(rowp + 1024 + c0 + v8 * 8);
#pragma unroll
        for (int i = 0; i < 8; ++i) {
            klds[lane][v8 * 8 + i] = bf2f((ushort_t)tk[i]);
            vlds[lane][v8 * 8 + i] = bf2f((ushort_t)tv[i]);
        }
    }
    __syncthreads();

    const float* rpb = branch ? rpb2 : rpb1;
    int code_i = 0;
    if (branch) {
        int gh = (hh < 56) ? 0 : (hh < 60 ? 1 : 2);
        int gw = (wp < 56) ? 0 : (wp < 60 ? 1 : 2);
        code_i = gh * 3 + gw;
    }

    float s[64];
    float mx = -1e30f;
#pragma unroll
    for (int j = 0; j < 64; ++j) {
        int rj = j >> 3, cj = j & 7;
        const float4* kr4 = (const float4*)&klds[j][0];
        float4 k0 = kr4[0], k1 = kr4[1], k2 = kr4[2], k3 = kr4[3];
        float4 k4 = kr4[4], k5 = kr4[5], k6 = kr4[6], k7 = kr4[7];
        float acc =
            q[0]*k0.x + q[1]*k0.y + q[2]*k0.z + q[3]*k0.w +
            q[4]*k1.x + q[5]*k1.y + q[6]*k1.z + q[7]*k1.w +
            q[8]*k2.x + q[9]*k2.y + q[10]*k2.z + q[11]*k2.w +
            q[12]*k3.x + q[13]*k3.y + q[14]*k3.z + q[15]*k3.w +
            q[16]*k4.x + q[17]*k4.y + q[18]*k4.z + q[19]*k4.w +
            q[20]*k5.x + q[21]*k5.y + q[22]*k5.z + q[23]*k5.w +
            q[24]*k6.x + q[25]*k6.y + q[26]*k6.z + q[27]*k6.w +
            q[28]*k7.x + q[29]*k7.y + q[30]*k7.z + q[31]*k7.w;
        float sc = acc * 0.17677669529663687f + rpb[((ti - rj) + (tj - cj) + 29) * 8 + head];
        if (branch) {
            int hj = wh * 8 + rj, wj = ww * 8 + cj;
            int gh = (hj < 56) ? 0 : (hj < 60 ? 1 : 2);
            int gw = (wj < 56) ? 0 : (wj < 60 ? 1 : 2);
            if (gh * 3 + gw != code_i) sc -= 100.f;
        }
        s[j] = sc;
        mx = fmaxf(mx, sc);
    }
    float sum = 0.f;
#pragma unroll
    for (int j = 0; j < 64; ++j) { float e = __expf(s[j] - mx); s[j] = e; sum += e; }
    float inv = 1.f / sum;
    float o[32];
#pragma unroll
    for (int d = 0; d < 32; ++d) o[d] = 0.f;
#pragma unroll
    for (int j = 0; j < 64; ++j) {
        float p = s[j] * inv;
        const float4* vr4 = (const float4*)&vlds[j][0];
#pragma unroll
        for (int d4 = 0; d4 < 8; ++d4) {
            float4 vv = vr4[d4];
            o[d4 * 4 + 0] += p * vv.x;
            o[d4 * 4 + 1] += p * vv.y;
            o[d4 * 4 + 2] += p * vv.z;
            o[d4 * 4 + 3] += p * vv.w;
        }
    }
    ushort_t* op = attno + (size_t)(b * 4096 + n) * 512 + c0;
#pragma unroll
    for (int v8 = 0; v8 < 4; ++v8) {
        short8 t;
#pragma unroll
        for (int i = 0; i < 8; ++i) t[i] = (short)f2bf(o[v8 * 8 + i]);
        *(short8*)(op + v8 * 8) = t;
    }
}

// ---------------------------------------------------------------------------
extern "C" void kernel_launch(void* const* d_in, const int* in_sizes, int n_in,
                              void* d_out, int out_size, void* d_ws, size_t ws_size,
                              hipStream_t stream) {
    const float* x      = (const float*)d_in[0];
    const float* style  = (const float*)d_in[1];
    const float* ada1_w = (const float*)d_in[2];
    const float* ada1_b = (const float*)d_in[3];
    const float* qkv_w  = (const float*)d_in[4];
    const float* qkv_b  = (const float*)d_in[5];
    const float* rpb1   = (const float*)d_in[6];
    const float* rpb2   = (const float*)d_in[7];
    const float* proj_w = (const float*)d_in[8];
    const float* proj_b = (const float*)d_in[9];
    const float* ada2_w = (const float*)d_in[10];
    const float* ada2_b = (const float*)d_in[11];
    const float* mlp_w1 = (const float*)d_in[12];
    const float* mlp_b1 = (const float*)d_in[13];
    const float* mlp_w2 = (const float*)d_in[14];
    const float* mlp_b2 = (const float*)d_in[15];
    float* outf = (float*)d_out;

    char* W = (char*)d_ws;
    ushort_t* qkvb    = (ushort_t*)(W);                      // 96 MB (32768 x 1536)
    ushort_t* attno   = (ushort_t*)(W + 100663296);          // 32 MB (32768 x 512)
    ushort_t* hbuf    = (ushort_t*)(W);                      // 128 MB overlay (32768 x 2048)
    ushort_t* xn      = (ushort_t*)(W + 134217728);          // 32 MB (32768 x 512)
    ushort_t* qkv_wb  = (ushort_t*)(W + 167772160);
    ushort_t* proj_wb = (ushort_t*)(W + 167772160 + 1572864);
    ushort_t* w1b     = (ushort_t*)(W + 167772160 + 2097152);
    ushort_t* w2b     = (ushort_t*)(W + 167772160 + 4194304);
    float* freg  = (float*)(W + 167772160 + 6291456);
    float* s1    = freg;
    float* s2    = freg + 8192;
    float* mean1 = freg + 16384;
    float* rstd1 = freg + 20480;
    float* mean2 = freg + 24576;
    float* rstd2 = freg + 28672;
    float* psum  = freg + 32768;    // 8*32*512
    float* psq   = freg + 163840;   // 8*32*512
    float* psum2 = freg + 294912;   // 8*512
    float* psq2  = freg + 303104;   // 8*512

    // fused weight conversion + stats-buffer zeroing
    conv_zero<<<12320, 256, 0, stream>>>(qkv_w, qkv_wb, proj_w, proj_wb,
                                         mlp_w1, w1b, mlp_w2, w2b, psum2, psq2);

    style_kernel<<<64, 256, 0, stream>>>(style, ada1_w, ada1_b, ada2_w, ada2_b, s1, s2);

    // adain1
    stats_part<<<256, 512, 0, stream>>>(x, psum, psq);
    stats_fin<<<16, 256, 0, stream>>>(psum, psq, mean1, rstd1);
    adain_kernel<<<16384, 256, 0, stream>>>(x, s1, mean1, rstd1, xn);

    // qkv: 768 tiles, gridN=6
    gemm256<0><<<256, 512, 0, stream>>>(xn, qkv_wb, qkv_b, nullptr, nullptr, qkvb,
                                        nullptr, nullptr, 1536, 512, 6, 768, 3);

    attn_kernel<<<8192, 64, 0, stream>>>(qkvb, rpb1, rpb2, attno);

    // proj + residual -> d_out (f32) + fused adain2 stats
    gemm256<1><<<256, 512, 0, stream>>>(attno, proj_wb, proj_b, x, outf, nullptr,
                                        psum2, psq2, 512, 512, 2, 256, 3);

    // adain2 (stats from proj epilogue)
    stats_fin2<<<16, 256, 0, stream>>>(psum2, psq2, mean2, rstd2);
    adain_kernel<<<16384, 256, 0, stream>>>(outf, s2, mean2, rstd2, xn);

    // mlp1: 1024 tiles, gridN=8
    gemm256<2><<<256, 512, 0, stream>>>(xn, w1b, mlp_b1, nullptr, nullptr, hbuf,
                                        nullptr, nullptr, 2048, 512, 8, 1024, 3);
    // mlp2: 256 tiles, gridN=2, K=2048 (nt=32)
    gemm256<3><<<256, 512, 0, stream>>>(hbuf, w2b, mlp_b2, nullptr, outf, nullptr,
                                        nullptr, nullptr, 512, 2048, 2, 256, 5);
}

// Round 6
// 443.097 us; speedup vs baseline: 1.6439x; 1.1457x over previous
//
#include <hip/hip_runtime.h>
#include <math.h>

typedef __attribute__((ext_vector_type(8))) short short8;
typedef __attribute__((ext_vector_type(4))) float f32x4;
typedef unsigned short ushort_t;
typedef unsigned long long ull_t;

__device__ __forceinline__ float bf2f(ushort_t u) {
    return __uint_as_float(((unsigned int)u) << 16);
}
__device__ __forceinline__ ushort_t f2bf(float f) {
    unsigned int u = __float_as_uint(f);
    unsigned int r = u + 0x7fffu + ((u >> 16) & 1u);   // RTN-even
    return (ushort_t)(r >> 16);
}
__device__ __forceinline__ unsigned cvt_pk_bf16(float lo, float hi) {
    unsigned r;
    asm volatile("v_cvt_pk_bf16_f32 %0, %1, %2" : "=v"(r) : "v"(lo), "v"(hi));
    return r;
}

__device__ __forceinline__ void async_cp16(const void* g, void* l) {
    __builtin_amdgcn_global_load_lds((const __attribute__((address_space(1))) void*)g,
                                     (__attribute__((address_space(3))) void*)l, 16, 0, 0);
}

// tanh-form gelu via hardware exp: max abs err ~3e-4*|x|
__device__ __forceinline__ float fast_gelu(float v) {
    float u2 = 2.0f * v * (0.7978845608028654f + 0.0356774081f * v * v);
    float e = __expf(u2);
    float r = 1.0f / (e + 1.0f);
    return v - v * r;
}

// ---------------------------------------------------------------------------
// fused setup: 4 weight conversions + zero psum2/psq2 + expanded bias tables
// tbl0[h][i][j] = rpb1[idx(i,j)*8+h]
// tbl1[h][cls][i][j] = rpb2[idx*8+h] + mask(cls,i,j); cls=(wh==7)*2|(ww==7)
// ---------------------------------------------------------------------------
__global__ __launch_bounds__(256) void conv_zero(
        const float* __restrict__ qkv_w, ushort_t* __restrict__ qkv_wb,
        const float* __restrict__ proj_w, ushort_t* __restrict__ proj_wb,
        const float* __restrict__ w1, ushort_t* __restrict__ w1b,
        const float* __restrict__ w2, ushort_t* __restrict__ w2b,
        float* __restrict__ psum2, float* __restrict__ psq2,
        const float* __restrict__ rpb1, const float* __restrict__ rpb2,
        float* __restrict__ tbl0, float* __restrict__ tbl1) {
    int i = blockIdx.x * 256 + threadIdx.x;
    if (i < 786432) {
        qkv_wb[i] = f2bf(qkv_w[i]);
    } else if (i < 1048576) {
        int j = i - 786432; proj_wb[j] = f2bf(proj_w[j]);
    } else if (i < 2097152) {
        int j = i - 1048576; w1b[j] = f2bf(w1[j]);
    } else if (i < 3145728) {
        int j = i - 2097152; w2b[j] = f2bf(w2[j]);
    } else if (i < 3153920) {
        int j = i - 3145728;       // [0, 8192)
        psum2[j] = 0.f; psq2[j] = 0.f;
    } else {
        int t = i - 3153920;       // [0, 163840)
        if (t < 32768) {
            int h = t >> 12, ij = t & 4095;
            int qi = ij >> 6, kj = ij & 63;
            int idx = ((qi >> 3) - (kj >> 3)) + ((qi & 7) - (kj & 7)) + 29;
            tbl0[t] = rpb1[idx * 8 + h];
        } else {
            int u = t - 32768;     // [0, 131072)
            int ij = u & 4095;
            int cls = (u >> 12) & 3;
            int h = u >> 14;
            int qi = ij >> 6, kj = ij & 63;
            int idx = ((qi >> 3) - (kj >> 3)) + ((qi & 7) - (kj & 7)) + 29;
            float v = rpb2[idx * 8 + h];
            int gh_i = (cls & 2) ? (((qi >> 3) < 4) ? 1 : 2) : 0;
            int gw_i = (cls & 1) ? (((qi & 7) < 4) ? 1 : 2) : 0;
            int gh_j = (cls & 2) ? (((kj >> 3) < 4) ? 1 : 2) : 0;
            int gw_j = (cls & 1) ? (((kj & 7) < 4) ? 1 : 2) : 0;
            if (gh_i * 3 + gw_i != gh_j * 3 + gw_j) v -= 100.f;
            tbl1[u] = v;
        }
    }
}

// ---------------------------------------------------------------------------
// style modulation: s = style @ (w/sqrt(512)).T + b
// ---------------------------------------------------------------------------
__global__ __launch_bounds__(256) void style_kernel(const float* __restrict__ style,
        const float* __restrict__ w1, const float* __restrict__ b1,
        const float* __restrict__ w2, const float* __restrict__ b2,
        float* __restrict__ s1, float* __restrict__ s2) {
    int t = blockIdx.x * 256 + threadIdx.x;
    int which = t >> 13;
    int idx = t & 8191;
    int b = idx >> 10, j = idx & 1023;
    const float* w = which ? w2 : w1;
    const float* bb = which ? b2 : b1;
    const float* st = style + b * 512;
    const float* wr = w + (size_t)j * 512;
    float acc = 0.f;
    for (int k = 0; k < 512; ++k) acc += st[k] * wr[k];
    float v = acc * 0.04419417382415922f + bb[j];
    (which ? s2 : s1)[idx] = v;
}

// ---------------------------------------------------------------------------
// instance-norm stats (adain1 path)
// ---------------------------------------------------------------------------
__global__ __launch_bounds__(512) void stats_part(const float* __restrict__ x,
        float* __restrict__ psum, float* __restrict__ psq) {
    int b = blockIdx.x >> 5;
    int ch = blockIdx.x & 31;
    int c = threadIdx.x;
    const float* p = x + ((size_t)b * 4096 + (size_t)ch * 128) * 512 + c;
    float s = 0.f, q = 0.f;
    for (int t = 0; t < 128; ++t) {
        float v = p[(size_t)t * 512];
        s += v; q += v * v;
    }
    psum[(size_t)blockIdx.x * 512 + c] = s;
    psq [(size_t)blockIdx.x * 512 + c] = q;
}

__global__ __launch_bounds__(256) void stats_fin(const float* __restrict__ psum,
        const float* __restrict__ psq, float* __restrict__ mean, float* __restrict__ rstd) {
    int i = blockIdx.x * 256 + threadIdx.x;
    int b = i >> 9, c = i & 511;
    float s = 0.f, q = 0.f;
    for (int ch = 0; ch < 32; ++ch) {
        s += psum[(size_t)(b * 32 + ch) * 512 + c];
        q += psq [(size_t)(b * 32 + ch) * 512 + c];
    }
    float m = s * (1.f / 4096.f);
    float v = q * (1.f / 4096.f) - m * m;
    mean[i] = m;
    rstd[i] = rsqrtf(v + 1e-5f);
}

// finalize from proj-epilogue atomics (direct [b][c] layout)
__global__ __launch_bounds__(256) void stats_fin2(const float* __restrict__ psum2,
        const float* __restrict__ psq2, float* __restrict__ mean, float* __restrict__ rstd) {
    int i = blockIdx.x * 256 + threadIdx.x;   // 4096
    float m = psum2[i] * (1.f / 4096.f);
    float v = psq2[i] * (1.f / 4096.f) - m * m;
    mean[i] = m;
    rstd[i] = rsqrtf(v + 1e-5f);
}

// ---------------------------------------------------------------------------
// adain apply
// ---------------------------------------------------------------------------
__global__ __launch_bounds__(256) void adain_kernel(const float* __restrict__ x,
        const float* __restrict__ s, const float* __restrict__ mean,
        const float* __restrict__ rstd, ushort_t* __restrict__ xn) {
    size_t i4 = (size_t)blockIdx.x * 256 + threadIdx.x;
    size_t e = i4 * 4;
    int b = (int)(e >> 21);
    int c = (int)(e & 511);
    float4 xv = *(const float4*)(x + e);
    float vals[4] = {xv.x, xv.y, xv.z, xv.w};
    ushort_t o[4];
#pragma unroll
    for (int j = 0; j < 4; ++j) {
        int cc = c + j;
        float g  = s[b * 1024 + cc];
        float be = s[b * 1024 + 512 + cc];
        float mn = mean[b * 512 + cc];
        float rs = rstd[b * 512 + cc];
        o[j] = f2bf(g * (vals[j] - mn) * rs + be);
    }
    ull_t packed = (ull_t)o[0] |
        ((ull_t)o[1] << 16) | ((ull_t)o[2] << 32) | ((ull_t)o[3] << 48);
    *(ull_t*)(xn + e) = packed;
}

// ---------------------------------------------------------------------------
// GEMM 256x256 tile, BK=64, 8 waves (2Mx4N), 4 phases/K-tile, persistent
// blocks (grid=256, tiles looped inside; pipeline continuous across tiles).
// vmcnt(4) drains own staging BEFORE the closing barrier (per-wave rule).
// EPI: 0 = bf16, 1 = +resid -> f32 + column stats atomics, 2 = gelu bf16,
//      3 = f32 +=
// ---------------------------------------------------------------------------
template<int EPI>
__global__ __launch_bounds__(512, 2) void gemm256(
        const ushort_t* __restrict__ A, const ushort_t* __restrict__ Bw,
        const float* __restrict__ bias, const float* __restrict__ resid,
        float* __restrict__ outf, ushort_t* __restrict__ outh,
        float* __restrict__ psum2, float* __restrict__ psq2,
        int N, int K, int gridN, int ntiles, int lnt) {
    __shared__ ushort_t lds[65536];   // 128 KiB
    const int tid  = threadIdx.x;
    const int lane = tid & 63;
    const int wave = tid >> 6;
    const int wm = wave >> 2, wn = wave & 3;
    const int lm = lane & 15;
    const int kg = lane >> 4;
    const int nt = 1 << lnt;
    const int tpb = ntiles >> 8;

    const int orig = blockIdx.x;               // grid fixed at 256
    const int wgid = (orig & 7) * 32 + (orig >> 3);   // XCD swizzle

    unsigned int lo0 = lm * 128 + ((kg * 16) ^ ((lm & 7) << 4));
    unsigned int lo1 = lo0 ^ 64;
    unsigned int vA0 = wm * 16384 + lo0;
    unsigned int vA1 = wm * 16384 + lo1;
    unsigned int vB0 = 65536 + (wn >> 1) * 16384 + (wn & 1) * 8192 + lo0;
    unsigned int vB1 = 65536 + (wn >> 1) * 16384 + (wn & 1) * 8192 + lo1;
    const char* ldsc = (const char*)lds;

    int off[2][2];
#pragma unroll
    for (int rnd = 0; rnd < 2; ++rnd) {
        int chunk = tid + rnd * 512;
        int row = chunk >> 3;
        int g = chunk & 7;
        int gsw = g ^ (row & 7);
#pragma unroll
        for (int h = 0; h < 2; ++h)
            off[h][rnd] = (h * 128 + row) * K + gsw * 8;
    }

    f32x4 acc[8][4];
#pragma unroll
    for (int m = 0; m < 8; ++m)
#pragma unroll
        for (int n = 0; n < 4; ++n)
#pragma unroll
            for (int r = 0; r < 4; ++r) acc[m][n][r] = 0.f;

    auto stage = [&](const ushort_t* __restrict__ mat, long bcur, long bnxt,
                     int dslot, int h, int tt, int isB) {
        long mb = (tt < nt) ? bcur : bnxt;
        int kt = tt & (nt - 1);
        const ushort_t* base = mat + mb + (kt << 6);
        ushort_t* dst = (ushort_t*)lds + isB * 32768 + dslot * 16384 + h * 8192 + tid * 8;
#pragma unroll
        for (int rnd = 0; rnd < 2; ++rnd)
            async_cp16(base + off[h][rnd], dst + rnd * 4096);
    };

    int tcur = wgid;
    int bm = tcur / gridN, bn = tcur - bm * gridN;
    long Am = (long)bm * 256 * K;
    long Bn = (long)bn * 256 * K;

    stage(A,  Am, Am, 0, 0, 0, 0); stage(A,  Am, Am, 0, 1, 0, 0);
    stage(Bw, Bn, Bn, 0, 0, 0, 1); stage(Bw, Bn, Bn, 0, 1, 0, 1);
    stage(Bw, Bn, Bn, 1, 0, 1, 1); stage(Bw, Bn, Bn, 1, 1, 1, 1);
    asm volatile("s_waitcnt vmcnt(4)" ::: "memory");
    __builtin_amdgcn_sched_barrier(0);
    __builtin_amdgcn_s_barrier();

    for (int ti = 0; ti < tpb; ++ti) {
        int tnxt = (ti + 1 < tpb) ? tcur + 256 : tcur;
        int bm2 = tnxt / gridN, bn2 = tnxt - bm2 * gridN;
        long Am2 = (long)bm2 * 256 * K;
        long Bn2 = (long)bn2 * 256 * K;

#pragma unroll 2
        for (int t = 0; t < nt; ++t) {
            const int c = t & 1;
            short8 bfr[4][2];
#pragma unroll
            for (int q = 0; q < 4; ++q) {
                short8 af[2][2];
#pragma unroll
                for (int mq = 0; mq < 2; ++mq) {
                    af[mq][0] = *(const short8*)(ldsc + vA0 + (q * 4096 + mq * 2048));
                    af[mq][1] = *(const short8*)(ldsc + vA1 + (q * 4096 + mq * 2048));
                }
                if (q == 0) {
#pragma unroll
                    for (int n = 0; n < 4; ++n) {
                        bfr[n][0] = *(const short8*)(ldsc + vB0 + n * 2048);
                        bfr[n][1] = *(const short8*)(ldsc + vB1 + n * 2048);
                    }
                }
                if      (q == 0) stage(A,  Am, Am2, c ^ 1, 0, t + 1, 0);
                else if (q == 1) stage(A,  Am, Am2, c ^ 1, 1, t + 1, 0);
                else if (q == 2) stage(Bw, Bn, Bn2, c,     0, t + 2, 1);
                else             stage(Bw, Bn, Bn2, c,     1, t + 2, 1);

                __builtin_amdgcn_s_barrier();
                asm volatile("s_waitcnt lgkmcnt(0)" ::: "memory");
                __builtin_amdgcn_sched_barrier(0);
                __builtin_amdgcn_s_setprio(1);
#pragma unroll
                for (int mq = 0; mq < 2; ++mq)
#pragma unroll
                    for (int n = 0; n < 4; ++n)
#pragma unroll
                        for (int ks = 0; ks < 2; ++ks)
                            acc[q * 2 + mq][n] = __builtin_amdgcn_mfma_f32_16x16x32_bf16(
                                af[mq][ks], bfr[n][ks], acc[q * 2 + mq][n], 0, 0, 0);
                __builtin_amdgcn_s_setprio(0);
                if (q == 3) {
                    asm volatile("s_waitcnt vmcnt(4)" ::: "memory");
                    __builtin_amdgcn_sched_barrier(0);
                }
                __builtin_amdgcn_s_barrier();
            }
            vA0 ^= 32768u; vA1 ^= 32768u; vB0 ^= 32768u; vB1 ^= 32768u;
        }

        const long tile_m = (long)bm * 256;
        const long tile_n = (long)bn * 256;
        float csum[4], csq[4];
        if (EPI == 1) {
#pragma unroll
            for (int n = 0; n < 4; ++n) { csum[n] = 0.f; csq[n] = 0.f; }
        }
#pragma unroll
        for (int m = 0; m < 8; ++m) {
            long row0 = tile_m + wm * 128 + m * 16 + kg * 4;
#pragma unroll
            for (int n = 0; n < 4; ++n) {
                long col = tile_n + wn * 64 + n * 16 + lm;
                float bb = bias[col];
#pragma unroll
                for (int r = 0; r < 4; ++r) {
                    long o = (row0 + r) * (long)N + col;
                    float v = acc[m][n][r] + bb;
                    if (EPI == 0) {
                        outh[o] = f2bf(v);
                    } else if (EPI == 1) {
                        float w = v + resid[o];
                        outf[o] = w;
                        csum[n] += w; csq[n] += w * w;
                    } else if (EPI == 2) {
                        outh[o] = f2bf(fast_gelu(v));
                    } else {
                        outf[o] += v;
                    }
                    acc[m][n][r] = 0.f;
                }
            }
        }
        if (EPI == 1) {
            int b = (int)(tile_m >> 12);
#pragma unroll
            for (int n = 0; n < 4; ++n) {
                int col = (int)(tile_n + wn * 64 + n * 16 + lm);
                atomicAdd(&psum2[b * 512 + col], csum[n]);
                atomicAdd(&psq2 [b * 512 + col], csq[n]);
            }
        }

        tcur = tnxt; bm = bm2; bn = bn2; Am = Am2; Bn = Bn2;
    }
}

// ---------------------------------------------------------------------------
// MFMA window attention: one wave per (branch, b, window, head) job.
// S^T = mfma(K, Q): lane holds S[i][j], i = lane&15 + 16ni, j = 16mj + 4kg + r.
// Softmax over j: in-lane 16 + shfl_xor(16,32). Bias from expanded tables.
// PV: O^T = mfma(V^T, P): V staged transposed in LDS, P bounced via LDS [i][j].
// Wave-private LDS slices -> no barriers at all.
// ---------------------------------------------------------------------------
__global__ __launch_bounds__(256) void attn_mfma(const ushort_t* __restrict__ qkv,
        const float* __restrict__ tbl0, const float* __restrict__ tbl1,
        ushort_t* __restrict__ attno) {
    __shared__ ushort_t lds[27648];   // 4 waves x (Vt [32][72] + P [64][72])
    const int tid = threadIdx.x;
    const int lane = tid & 63;
    const int wave = tid >> 6;
    const int job = blockIdx.x * 4 + wave;     // 8192 jobs
    const int branch = job >> 12;
    const int w_idx  = (job >> 3) & 511;
    const int head   = job & 7;
    const int b = w_idx >> 6, win = w_idx & 63;
    const int wh = win >> 3, ww = win & 7;
    const int c0 = branch * 256 + head * 32;
    const int i_lo = lane & 15;
    const int kg = lane >> 4;

    ushort_t* Vt = lds + wave * 6912;          // [32][72] bf16
    ushort_t* P  = lds + wave * 6912 + 2304;   // [64][72] bf16

    // token map: window pos p -> global token (roll cancels for shifted branch)
    auto tokof = [&](int p) {
        int hh = wh * 8 + (p >> 3), wp = ww * 8 + (p & 7);
        if (branch) { hh = (hh + 4) & 63; wp = (wp + 4) & 63; }
        return b * 4096 + hh * 64 + wp;
    };

    // ---- stage V transposed: lane = token p, writes Vt[d][p] ----
    {
        const ushort_t* vp = qkv + (size_t)tokof(lane) * 1536 + 1024 + c0;
        short8 v0 = *(const short8*)(vp);
        short8 v1 = *(const short8*)(vp + 8);
        short8 v2 = *(const short8*)(vp + 16);
        short8 v3 = *(const short8*)(vp + 24);
#pragma unroll
        for (int e = 0; e < 8; ++e) {
            Vt[(e     ) * 72 + lane] = (ushort_t)v0[e];
            Vt[(e +  8) * 72 + lane] = (ushort_t)v1[e];
            Vt[(e + 16) * 72 + lane] = (ushort_t)v2[e];
            Vt[(e + 24) * 72 + lane] = (ushort_t)v3[e];
        }
    }

    // ---- K/Q fragments (row = token 16m + i_lo, d-slice = kg*8..+8) ----
    short8 kf[4], qf[4];
#pragma unroll
    for (int m = 0; m < 4; ++m) {
        size_t rowb = (size_t)tokof(m * 16 + i_lo) * 1536;
        kf[m] = *(const short8*)(qkv + rowb + 512 + c0 + kg * 8);
        qf[m] = *(const short8*)(qkv + rowb + c0 + kg * 8);
    }

    // ---- S^T = K * Q^T : 16 MFMA ----
    f32x4 s[4][4];   // [mj][ni]
#pragma unroll
    for (int mj = 0; mj < 4; ++mj)
#pragma unroll
        for (int ni = 0; ni < 4; ++ni)
#pragma unroll
            for (int r = 0; r < 4; ++r) s[mj][ni][r] = 0.f;
#pragma unroll
    for (int mj = 0; mj < 4; ++mj)
#pragma unroll
        for (int ni = 0; ni < 4; ++ni)
            s[mj][ni] = __builtin_amdgcn_mfma_f32_16x16x32_bf16(kf[mj], qf[ni], s[mj][ni], 0, 0, 0);

    // ---- scale + bias (expanded table, [i][j] layout) ----
    const float* tb;
    if (branch == 0) {
        tb = tbl0 + head * 4096;
    } else {
        int cls = ((wh == 7) ? 2 : 0) | ((ww == 7) ? 1 : 0);
        tb = tbl1 + (head * 4 + cls) * 4096;
    }
#pragma unroll
    for (int ni = 0; ni < 4; ++ni) {
        int i = ni * 16 + i_lo;
#pragma unroll
        for (int mj = 0; mj < 4; ++mj) {
            float4 bv = *(const float4*)(tb + i * 64 + mj * 16 + kg * 4);
            s[mj][ni][0] = s[mj][ni][0] * 0.17677669529663687f + bv.x;
            s[mj][ni][1] = s[mj][ni][1] * 0.17677669529663687f + bv.y;
            s[mj][ni][2] = s[mj][ni][2] * 0.17677669529663687f + bv.z;
            s[mj][ni][3] = s[mj][ni][3] * 0.17677669529663687f + bv.w;
        }
    }

    // ---- softmax over j (rows of S^T): in-lane + cross-kg shfl ----
    float mx[4], rs[4];
#pragma unroll
    for (int ni = 0; ni < 4; ++ni) {
        float m = -1e30f;
#pragma unroll
        for (int mj = 0; mj < 4; ++mj)
#pragma unroll
            for (int r = 0; r < 4; ++r) m = fmaxf(m, s[mj][ni][r]);
        m = fmaxf(m, __shfl_xor(m, 16));
        m = fmaxf(m, __shfl_xor(m, 32));
        mx[ni] = m;
    }
#pragma unroll
    for (int ni = 0; ni < 4; ++ni) {
        float sum = 0.f;
#pragma unroll
        for (int mj = 0; mj < 4; ++mj)
#pragma unroll
            for (int r = 0; r < 4; ++r) {
                float e = __expf(s[mj][ni][r] - mx[ni]);
                s[mj][ni][r] = e;
                sum += e;
            }
        sum += __shfl_xor(sum, 16);
        sum += __shfl_xor(sum, 32);
        rs[ni] = sum;
    }

    // ---- pack P to bf16, bounce via LDS [i][j] (stride 72) ----
#pragma unroll
    for (int ni = 0; ni < 4; ++ni) {
        int i = ni * 16 + i_lo;
#pragma unroll
        for (int mj = 0; mj < 4; ++mj) {
            unsigned w0 = cvt_pk_bf16(s[mj][ni][0], s[mj][ni][1]);
            unsigned w1 = cvt_pk_bf16(s[mj][ni][2], s[mj][ni][3]);
            ull_t w = (ull_t)w0 | ((ull_t)w1 << 32);
            *(ull_t*)&P[i * 72 + mj * 16 + kg * 4] = w;
        }
    }
    asm volatile("s_waitcnt lgkmcnt(0)" ::: "memory");
    __builtin_amdgcn_sched_barrier(0);

    // ---- PV: O^T[d][i] = sum_j V^T[d][j] * P[i][j] : 16 MFMA ----
    short8 va[2][2];   // [md][ks]
    short8 pb[4][2];   // [ni][ks]
#pragma unroll
    for (int md = 0; md < 2; ++md)
#pragma unroll
        for (int ks = 0; ks < 2; ++ks)
            va[md][ks] = *(const short8*)&Vt[(md * 16 + i_lo) * 72 + ks * 32 + kg * 8];
#pragma unroll
    for (int ni = 0; ni < 4; ++ni)
#pragma unroll
        for (int ks = 0; ks < 2; ++ks)
            pb[ni][ks] = *(const short8*)&P[(ni * 16 + i_lo) * 72 + ks * 32 + kg * 8];

    f32x4 o[2][4];   // [md][ni]
#pragma unroll
    for (int md = 0; md < 2; ++md)
#pragma unroll
        for (int ni = 0; ni < 4; ++ni)
#pragma unroll
            for (int r = 0; r < 4; ++r) o[md][ni][r] = 0.f;
#pragma unroll
    for (int md = 0; md < 2; ++md)
#pragma unroll
        for (int ni = 0; ni < 4; ++ni)
#pragma unroll
            for (int ks = 0; ks < 2; ++ks)
                o[md][ni] = __builtin_amdgcn_mfma_f32_16x16x32_bf16(va[md][ks], pb[ni][ks], o[md][ni], 0, 0, 0);

    // ---- normalize + store: lane holds O[i = 16ni+i_lo][d = 16md+4kg+r] ----
#pragma unroll
    for (int ni = 0; ni < 4; ++ni) {
        float inv = 1.f / rs[ni];
        ushort_t* op = attno + (size_t)tokof(ni * 16 + i_lo) * 512 + c0;
#pragma unroll
        for (int md = 0; md < 2; ++md) {
            ushort_t h0 = f2bf(o[md][ni][0] * inv);
            ushort_t h1 = f2bf(o[md][ni][1] * inv);
            ushort_t h2 = f2bf(o[md][ni][2] * inv);
            ushort_t h3 = f2bf(o[md][ni][3] * inv);
            ull_t w = (ull_t)h0 | ((ull_t)h1 << 16) | ((ull_t)h2 << 32) | ((ull_t)h3 << 48);
            *(ull_t*)(op + md * 16 + kg * 4) = w;
        }
    }
}

// ---------------------------------------------------------------------------
extern "C" void kernel_launch(void* const* d_in, const int* in_sizes, int n_in,
                              void* d_out, int out_size, void* d_ws, size_t ws_size,
                              hipStream_t stream) {
    const float* x      = (const float*)d_in[0];
    const float* style  = (const float*)d_in[1];
    const float* ada1_w = (const float*)d_in[2];
    const float* ada1_b = (const float*)d_in[3];
    const float* qkv_w  = (const float*)d_in[4];
    const float* qkv_b  = (const float*)d_in[5];
    const float* rpb1   = (const float*)d_in[6];
    const float* rpb2   = (const float*)d_in[7];
    const float* proj_w = (const float*)d_in[8];
    const float* proj_b = (const float*)d_in[9];
    const float* ada2_w = (const float*)d_in[10];
    const float* ada2_b = (const float*)d_in[11];
    const float* mlp_w1 = (const float*)d_in[12];
    const float* mlp_b1 = (const float*)d_in[13];
    const float* mlp_w2 = (const float*)d_in[14];
    const float* mlp_b2 = (const float*)d_in[15];
    float* outf = (float*)d_out;

    char* W = (char*)d_ws;
    ushort_t* qkvb    = (ushort_t*)(W);                      // 96 MB (32768 x 1536)
    ushort_t* attno   = (ushort_t*)(W + 100663296);          // 32 MB (32768 x 512)
    ushort_t* hbuf    = (ushort_t*)(W);                      // 128 MB overlay (32768 x 2048)
    ushort_t* xn      = (ushort_t*)(W + 134217728);          // 32 MB (32768 x 512)
    ushort_t* qkv_wb  = (ushort_t*)(W + 167772160);
    ushort_t* proj_wb = (ushort_t*)(W + 167772160 + 1572864);
    ushort_t* w1b     = (ushort_t*)(W + 167772160 + 2097152);
    ushort_t* w2b     = (ushort_t*)(W + 167772160 + 4194304);
    float* freg  = (float*)(W + 167772160 + 6291456);
    float* s1    = freg;
    float* s2    = freg + 8192;
    float* mean1 = freg + 16384;
    float* rstd1 = freg + 20480;
    float* mean2 = freg + 24576;
    float* rstd2 = freg + 28672;
    float* psum  = freg + 32768;    // 8*32*512
    float* psq   = freg + 163840;   // 8*32*512
    float* psum2 = freg + 294912;   // 8*512
    float* psq2  = freg + 303104;   // 8*512
    float* tbl0  = freg + 311296;   // 8*64*64
    float* tbl1  = freg + 344064;   // 8*4*64*64 (ends at 475136 floats)

    // fused weight conversion + stats zeroing + bias-table expansion
    conv_zero<<<12960, 256, 0, stream>>>(qkv_w, qkv_wb, proj_w, proj_wb,
                                         mlp_w1, w1b, mlp_w2, w2b, psum2, psq2,
                                         rpb1, rpb2, tbl0, tbl1);

    style_kernel<<<64, 256, 0, stream>>>(style, ada1_w, ada1_b, ada2_w, ada2_b, s1, s2);

    // adain1
    stats_part<<<256, 512, 0, stream>>>(x, psum, psq);
    stats_fin<<<16, 256, 0, stream>>>(psum, psq, mean1, rstd1);
    adain_kernel<<<16384, 256, 0, stream>>>(x, s1, mean1, rstd1, xn);

    // qkv: 768 tiles, gridN=6
    gemm256<0><<<256, 512, 0, stream>>>(xn, qkv_wb, qkv_b, nullptr, nullptr, qkvb,
                                        nullptr, nullptr, 1536, 512, 6, 768, 3);

    // window attention (both branches), MFMA path
    attn_mfma<<<2048, 256, 0, stream>>>(qkvb, tbl0, tbl1, attno);

    // proj + residual -> d_out (f32) + fused adain2 stats
    gemm256<1><<<256, 512, 0, stream>>>(attno, proj_wb, proj_b, x, outf, nullptr,
                                        psum2, psq2, 512, 512, 2, 256, 3);

    // adain2 (stats from proj epilogue)
    stats_fin2<<<16, 256, 0, stream>>>(psum2, psq2, mean2, rstd2);
    adain_kernel<<<16384, 256, 0, stream>>>(outf, s2, mean2, rstd2, xn);

    // mlp1: 1024 tiles, gridN=8
    gemm256<2><<<256, 512, 0, stream>>>(xn, w1b, mlp_b1, nullptr, nullptr, hbuf,
                                        nullptr, nullptr, 2048, 512, 8, 1024, 3);
    // mlp2: 256 tiles, gridN=2, K=2048 (nt=32)
    gemm256<3><<<256, 512, 0, stream>>>(hbuf, w2b, mlp_b2, nullptr, outf, nullptr,
                                        nullptr, nullptr, 512, 2048, 2, 256, 5);
}